// Round 9
// baseline (265.649 us; speedup 1.0000x reference)
//
#include <hip/hip_runtime.h>
#include <stdint.h>

#define H_ 16
#define S_ 4096
#define D_ 64
#define ROWSTRIDE (H_ * D_)   // 1024 floats between consecutive s rows
#define BK 64                 // keys per packed tile
#define NT (S_ / BK)          // 64 key tiles per head
#define TILE_USH (BK * D_)    // 4096 ushorts per packed 64x64 bf16 tile
#define NBUF 4                // ring depth (tiles) -> 64 KB; 1 block/CU so LDS is free
#define BUF_USH (2 * TILE_USH)// K + V^T per ring slot = 16 KB
#define QB 256                // q-rows per block (4 fat waves x 64 q + producer)
#define LP 72
#define LK 72
#define QSCALE (0.125f * 1.44269504088896340736f)  // sm_scale * log2(e)
#define LOG2E 1.44269504088896340736f
#define SM_SCALE 0.125f

typedef unsigned short ushort_t;
typedef __attribute__((ext_vector_type(8))) __bf16 bf16x8;
typedef __attribute__((ext_vector_type(16))) float floatx16;
typedef __attribute__((ext_vector_type(8))) unsigned short ushortx8;
typedef __attribute__((ext_vector_type(4))) unsigned short ushortx4;

// exp2: single trans-pipe instruction. If the builtin is absent, the libm
// exp2f call may expand to several VALU ops -- force the raw v_exp_f32
// (denorm flush below 2^-126 is fine for softmax terms).
#if __has_builtin(__builtin_amdgcn_exp2f)
#define EXP2F(x) __builtin_amdgcn_exp2f(x)
#else
__device__ inline float exp2_hw(float x) {
    float r; asm("v_exp_f32 %0, %1" : "=v"(r) : "v"(x)); return r;
}
#define EXP2F(x) exp2_hw(x)
#endif

__device__ inline unsigned short f2bf(float x) {   // RNE fp32->bf16 (scalar path)
    union { float f; unsigned int u; } c; c.f = x;
    unsigned int r = c.u + 0x7fffu + ((c.u >> 16) & 1u);
    return (unsigned short)(r >> 16);
}
// packed 2xfp32 -> 2xbf16 (RNE). m240: NO clang builtin on gfx950 -- use
// a single v_cvt_pk_bf16_f32 via inline asm (lo=a, hi=b, RNE). Proven R8:
// this alone was 100 -> 83.5 us (VALUBusy 52 -> 38).
__device__ inline uint32_t cvt_pk_bf16(float a, float b) {
#if __has_builtin(__builtin_amdgcn_cvt_pk_bf16_f32)
    auto r = __builtin_amdgcn_cvt_pk_bf16_f32(a, b);
    uint32_t u; __builtin_memcpy(&u, &r, 4); return u;
#else
    uint32_t r;
    asm("v_cvt_pk_bf16_f32 %0, %1, %2" : "=v"(r) : "v"(a), "v"(b));
    return r;
#endif
}
// C-layout -> B-operand half exchange (one v_permlane32_swap_b32 if available)
__device__ inline void permswap(uint32_t& a, uint32_t& b, int g2) {
#if __has_builtin(__builtin_amdgcn_permlane32_swap)
    auto r = __builtin_amdgcn_permlane32_swap(a, b, false, false);
    uint32_t tmp[2]; __builtin_memcpy(tmp, &r, 8);
    a = tmp[0]; b = tmp[1];
#else
    uint32_t ra = (uint32_t)__shfl_xor((int)a, 32, 64);
    uint32_t rb = (uint32_t)__shfl_xor((int)b, 32, 64);
    uint32_t na = g2 ? rb : a;
    uint32_t nb = g2 ? b : ra;
    a = na; b = nb;
#endif
}
__device__ inline bf16x8 as_bf16x8(ushortx8 v) {
    union { ushortx8 s; bf16x8 b; } c; c.s = v; return c.b;
}
__device__ inline bf16x8 bf16x8_from_u32(uint32_t a, uint32_t b, uint32_t c, uint32_t d) {
    union { uint32_t u[4]; bf16x8 b; } x; x.u[0]=a; x.u[1]=b; x.u[2]=c; x.u[3]=d; return x.b;
}
__device__ inline ushortx8 ushortx8_from_u32(uint32_t a, uint32_t b, uint32_t c, uint32_t d) {
    union { uint32_t u[4]; ushortx8 s; } x; x.u[0]=a; x.u[1]=b; x.u[2]=c; x.u[3]=d; return x.s;
}
__device__ inline void glds16(const void* g, void* l) {
    __builtin_amdgcn_global_load_lds(
        (const __attribute__((address_space(1))) void*)g,
        (__attribute__((address_space(3))) void*)l, 16, 0, 0);
}

// ---------------------------------------------------------------------------
// Pre-pass (proven zero-conflict): FRAGMENT-ORDERED packed tiles.
// K tile frag f=mk*4+c (1 KB): (lane,j) = K[tile*64+mk*32+(lane&31)][(2c+(lane>>5))*8+j]
// V tile frag f=md*4+kc (1 KB): (lane,j) = V[tile*64+(2kc+(lane>>5))*8+j][md*32+(lane&31)]
// Main-kernel frag reads are ds_read_b128 at (base + f*1024B + lane*16B):
// lane-linear => zero bank conflicts, zero swizzle VALU; staging = linear copy.
// ---------------------------------------------------------------------------
__global__ __launch_bounds__(256)
void pack_kv(const float* __restrict__ K, const float* __restrict__ V,
             ushort_t* __restrict__ Kp, ushort_t* __restrict__ Vp) {
    __shared__ ushort_t lT[D_ * 88];   // V^T scratch: lT[d*88 + key]
    const int tid = threadIdx.x;
    const int h = blockIdx.x & (H_ - 1);
    const int tile = blockIdx.x >> 4;
    ushort_t* kout = Kp + (size_t)(h * NT + tile) * TILE_USH;
    ushort_t* vout = Vp + (size_t)(h * NT + tile) * TILE_USH;

    #pragma unroll
    for (int p = 0; p < 2; ++p) {
        int idx = tid + p * 256;       // 0..511
        int f = idx >> 6;              // frag 0..7
        int lo = idx & 63;
        int mk = f >> 2, c = f & 3;
        int l31 = lo & 31, g2 = lo >> 5;
        const float* kp = K + (size_t)(tile * BK + mk * 32 + l31) * ROWSTRIDE + h * D_ + (2 * c + g2) * 8;
        float4 a = *(const float4*)kp;
        float4 b = *(const float4*)(kp + 4);
        *(ushortx8*)&kout[f * 512 + lo * 8] = ushortx8_from_u32(
            cvt_pk_bf16(a.x, a.y), cvt_pk_bf16(a.z, a.w),
            cvt_pk_bf16(b.x, b.y), cvt_pk_bf16(b.z, b.w));
    }

    #pragma unroll
    for (int p = 0; p < 4; ++p) {
        int idx = tid + p * 256;
        int row = idx >> 4;            // key 0..63
        int d4 = (idx & 15) * 4;
        const float* vp = V + (size_t)(tile * BK + row) * ROWSTRIDE + h * D_ + d4;
        float4 vv = *(const float4*)vp;
        lT[(d4 + 0) * 88 + row] = f2bf(vv.x);
        lT[(d4 + 1) * 88 + row] = f2bf(vv.y);
        lT[(d4 + 2) * 88 + row] = f2bf(vv.z);
        lT[(d4 + 3) * 88 + row] = f2bf(vv.w);
    }
    __syncthreads();
    #pragma unroll
    for (int p = 0; p < 2; ++p) {
        int idx = tid + p * 256;
        int f = idx >> 6;
        int lo = idx & 63;
        int md = f >> 2, kc = f & 3;
        int l31 = lo & 31, g2 = lo >> 5;
        ushortx8 u = *(ushortx8*)&lT[(md * 32 + l31) * 88 + (2 * kc + g2) * 8];
        *(ushortx8*)&vout[f * 512 + lo * 8] = u;
    }
}

// ---------------------------------------------------------------------------
// R16 main kernel: R8 fat-wave structure (proven 83.5 us) + CROSS-TILE
// SOFTWARE PIPELINE. At 1 consumer wave/SIMD the binding constraint is the
// in-order issue of the serial QK(t)->exp(t)->PV(t) chain: exp waits ~300 cyc
// for the QK accumulator chains to drain, and the MFMA pipe idles through the
// 512-cyc exp2 trans stream. Pipelined order {QK(t+1); FIN(t)} makes exp(t)
// depend on MFMAs issued a full phase earlier (no drain wait) and lets the
// exp(t) trans stream issue while QK(t+1) occupies the MFMA pipe; PV(t)
// queues behind QK(t+1), keeping the matrix pipe fed. (R1 tried this shape at
// 2.5 waves/SIMD where TLP masked ILP -> exact null; we are now in the
// 1-wave/SIMD regime the technique requires.) NBUF=4 gives the needed slack:
// consumer waits staged(t+1) before marking consumed(t); producer needs
// consumed >= t-2 at that point -- satisfied. stA/stB named buffers keep all
// indexing static (no scratch). Math identical to R8.
// ---------------------------------------------------------------------------
__global__ __launch_bounds__(320)
void usp_attn_fa8(const float* __restrict__ Q, const ushort_t* __restrict__ Kp,
                  const ushort_t* __restrict__ Vp, float* __restrict__ O) {
    __shared__ __attribute__((aligned(16))) ushort_t smem[NBUF * BUF_USH];  // 64 KB ring
    __shared__ int flags[8];   // [0]=tiles staged; [4+w]=tiles consumed by wave w

    const int tid = threadIdx.x;
    const int lane = tid & 63;
    const int wv = tid >> 6;          // 0..3 consumers, 4 producer
    const int h = blockIdx.x & (H_ - 1);
    const int qi = blockIdx.x >> 4;   // 0..15 (256 q-rows per block)
    const int l31 = lane & 31;
    const int g2 = lane >> 5;

    if (tid < 8) flags[tid] = 0;
    __syncthreads();                  // only block-wide barrier

    const ushort_t* kbase = Kp + (size_t)h * NT * TILE_USH;
    const ushort_t* vbase = Vp + (size_t)h * NT * TILE_USH;

    if (wv == 4) {
        // ---------------- producer ----------------
        for (int t = 0; t < NT; ++t) {
            if (t >= NBUF) {
                for (;;) {
                    int m0 = __hip_atomic_load(&flags[4], __ATOMIC_ACQUIRE, __HIP_MEMORY_SCOPE_WORKGROUP);
                    int m1 = __hip_atomic_load(&flags[5], __ATOMIC_ACQUIRE, __HIP_MEMORY_SCOPE_WORKGROUP);
                    int m2 = __hip_atomic_load(&flags[6], __ATOMIC_ACQUIRE, __HIP_MEMORY_SCOPE_WORKGROUP);
                    int m3 = __hip_atomic_load(&flags[7], __ATOMIC_ACQUIRE, __HIP_MEMORY_SCOPE_WORKGROUP);
                    if (min(min(m0, m1), min(m2, m3)) >= t - (NBUF - 1)) break;
                    __builtin_amdgcn_s_sleep(1);
                }
            }
            const ushort_t* gK = kbase + (size_t)t * TILE_USH;
            const ushort_t* gV = vbase + (size_t)t * TILE_USH;
            ushort_t* bK = smem + (t & (NBUF - 1)) * BUF_USH;
            ushort_t* bV = bK + TILE_USH;
            #pragma unroll
            for (int i = 0; i < 8; ++i) {
                glds16(gK + i * 512 + lane * 8, bK + i * 512);
                glds16(gV + i * 512 + lane * 8, bV + i * 512);
            }
            __builtin_amdgcn_s_waitcnt(0x0f70);   // vmcnt(0) producer-local drain
            __hip_atomic_store(&flags[0], t + 1, __ATOMIC_RELEASE, __HIP_MEMORY_SCOPE_WORKGROUP);
        }
        return;
    }

    // ---------------- consumer: 64 q-rows (2 halves of 32), pipelined -------
    const int q0 = qi * QB + wv * 64;

    // Q^T B-frags per half: B[k: d=c*16+g2*8+j][n: q=l31], pre-scaled (log2)
    bf16x8 qf[2][4];
    #pragma unroll
    for (int qh = 0; qh < 2; ++qh) {
        const float* qp = Q + (size_t)(q0 + qh * 32 + l31) * ROWSTRIDE + h * D_ + g2 * 8;
        #pragma unroll
        for (int c = 0; c < 4; ++c) {
            const float4 v0 = *(const float4*)(qp + c * 16);
            const float4 v1 = *(const float4*)(qp + c * 16 + 4);
            qf[qh][c] = bf16x8_from_u32(
                cvt_pk_bf16(v0.x * QSCALE, v0.y * QSCALE),
                cvt_pk_bf16(v0.z * QSCALE, v0.w * QSCALE),
                cvt_pk_bf16(v1.x * QSCALE, v1.y * QSCALE),
                cvt_pk_bf16(v1.z * QSCALE, v1.w * QSCALE));
        }
    }

    floatx16 o[2][2] = {{{0,0,0,0,0,0,0,0,0,0,0,0,0,0,0,0},
                         {0,0,0,0,0,0,0,0,0,0,0,0,0,0,0,0}},
                        {{0,0,0,0,0,0,0,0,0,0,0,0,0,0,0,0},
                         {0,0,0,0,0,0,0,0,0,0,0,0,0,0,0,0}}};
    float rsa[2][2] = {{0.f, 0.f}, {0.f, 0.f}};   // per (qh, mk) partials
    floatx16 stA[2][2], stB[2][2];

#define WAIT_STAGED(tt)                                                                             \
    while (__hip_atomic_load(&flags[0], __ATOMIC_ACQUIRE, __HIP_MEMORY_SCOPE_WORKGROUP) < (tt) + 1) \
        __builtin_amdgcn_s_sleep(1);

    // S^T = K Q^T for tile tt into st (K frags read once, both q-halves)
    auto qk = [&](int tt, floatx16 (&st)[2][2]) {
        const ushortx8* fp = (const ushortx8*)(smem + (tt & (NBUF - 1)) * BUF_USH) + lane;
        bf16x8 kk[8];
        #pragma unroll
        for (int f = 0; f < 8; ++f) kk[f] = as_bf16x8(fp[f * 64]);
        #pragma unroll
        for (int qh = 0; qh < 2; ++qh) {
            #pragma unroll
            for (int mk = 0; mk < 2; ++mk) {
                floatx16 acc = {0,0,0,0,0,0,0,0,0,0,0,0,0,0,0,0};
                #pragma unroll
                for (int c = 0; c < 4; ++c)
                    acc = __builtin_amdgcn_mfma_f32_32x32x16_bf16(kk[mk * 4 + c], qf[qh][c], acc, 0, 0, 0);
                st[qh][mk] = acc;
            }
        }
    };

    // exp2 + pack + PV for tile tt (V frags read once, both q-halves)
    auto fin = [&](floatx16 (&st)[2][2], int tt) {
        const ushortx8* fp = (const ushortx8*)(smem + (tt & (NBUF - 1)) * BUF_USH) + lane;
        bf16x8 vv[8];
        #pragma unroll
        for (int f = 0; f < 8; ++f) vv[f] = as_bf16x8(fp[512 + f * 64]);

        uint32_t qd[2][2][8];
        #pragma unroll
        for (int qh = 0; qh < 2; ++qh) {
            #pragma unroll
            for (int mk = 0; mk < 2; ++mk) {
                #pragma unroll
                for (int i = 0; i < 8; ++i) {
                    float p0 = EXP2F(st[qh][mk][2 * i]);
                    float p1 = EXP2F(st[qh][mk][2 * i + 1]);
                    rsa[qh][mk] += p0 + p1;
                    qd[qh][mk][i] = cvt_pk_bf16(p0, p1);
                }
            }
        }

        #pragma unroll
        for (int kc = 0; kc < 4; ++kc) {
            int mk = kc >> 1, ci = kc & 1;
            #pragma unroll
            for (int qh = 0; qh < 2; ++qh) {
                uint32_t a0 = qd[qh][mk][ci * 4 + 0], a1 = qd[qh][mk][ci * 4 + 1];
                uint32_t b0 = qd[qh][mk][ci * 4 + 2], b1 = qd[qh][mk][ci * 4 + 3];
                permswap(a0, b0, g2);
                permswap(a1, b1, g2);
                bf16x8 pf = bf16x8_from_u32(a0, a1, b0, b1);
                #pragma unroll
                for (int md = 0; md < 2; ++md)
                    o[qh][md] = __builtin_amdgcn_mfma_f32_32x32x16_bf16(vv[md * 4 + kc], pf, o[qh][md], 0, 0, 0);
            }
        }

        __hip_atomic_store(&flags[4 + wv], tt + 1, __ATOMIC_RELEASE, __HIP_MEMORY_SCOPE_WORKGROUP);
    };

    WAIT_STAGED(0);
    qk(0, stA);
    for (int t = 0; t < NT; t += 2) {          // NT even
        WAIT_STAGED(t + 1);
        qk(t + 1, stB);                        // QK(t+1) MFMAs overlap exp/PV(t)
        fin(stA, t);
        if (t + 2 < NT) { WAIT_STAGED(t + 2); qk(t + 2, stA); }
        fin(stB, t + 1);
    }
#undef WAIT_STAGED

    // --- epilogue (per half, identical to proven R8 epilogue)
    #pragma unroll
    for (int qh = 0; qh < 2; ++qh) {
        float r = rsa[qh][0] + rsa[qh][1];
        r += __shfl_xor(r, 32, 64);
        float inv = 1.f / r;
        float* op = O + (size_t)(q0 + qh * 32 + l31) * ROWSTRIDE + h * D_;
        #pragma unroll
        for (int md = 0; md < 2; ++md) {
            #pragma unroll
            for (int rq = 0; rq < 4; ++rq) {
                int d0 = md * 32 + rq * 8 + 4 * g2;   // C row = (reg&3)+8*(reg>>2)+4*g2
                float4 w;
                w.x = o[qh][md][4 * rq + 0] * inv;
                w.y = o[qh][md][4 * rq + 1] * inv;
                w.z = o[qh][md][4 * rq + 2] * inv;
                w.w = o[qh][md][4 * rq + 3] * inv;
                *(float4*)&op[d0] = w;
            }
        }
    }
}

// ---------------------------------------------------------------------------
// Fallback (proven R1 kernel) if ws can't hold packed K/V.
// ---------------------------------------------------------------------------
__global__ __launch_bounds__(256, 2)
void usp_attn_fa(const float* __restrict__ Q, const float* __restrict__ K,
                 const float* __restrict__ V, float* __restrict__ O) {
    __shared__ unsigned short fK[BK * LK];
    __shared__ unsigned short fVT[D_ * LK];
    __shared__ unsigned short fP[4 * 16 * LP];
    const int tid = threadIdx.x;
    const int lane = tid & 63;
    const int wv = tid >> 6;
    const int h = blockIdx.x & (H_ - 1);
    const int qt = blockIdx.x >> 4;
    const int q0 = qt * 64 + wv * 16;
    const int m16 = lane & 15;
    const int g = lane >> 4;
    typedef __attribute__((ext_vector_type(4))) float f4;
    bf16x8 qf[2];
    {
        const float* qp = Q + (size_t)(q0 + m16) * ROWSTRIDE + h * D_ + g * 8;
        for (int c = 0; c < 2; ++c) {
            ushortx8 u;
            #pragma unroll
            for (int j = 0; j < 8; ++j) u[j] = f2bf(qp[c * 32 + j]);
            qf[c] = as_bf16x8(u);
        }
    }
    f4 o[4] = {{0,0,0,0},{0,0,0,0},{0,0,0,0},{0,0,0,0}};
    float mrow[4] = {-1e30f,-1e30f,-1e30f,-1e30f};
    float lrow[4] = {0.f,0.f,0.f,0.f};
    unsigned short* myP = &fP[wv * 16 * LP];
    for (int k0 = 0; k0 < S_; k0 += BK) {
        __syncthreads();
        #pragma unroll
        for (int p = 0; p < 4; ++p) {
            int idx = tid + p * 256;
            int row = idx >> 4;
            int c4 = (idx & 15) * 4;
            const float* kp = K + (size_t)(k0 + row) * ROWSTRIDE + h * D_ + c4;
            float4 kv = *(const float4*)kp;
            ushortx4 ku;
            ku[0] = f2bf(kv.x); ku[1] = f2bf(kv.y); ku[2] = f2bf(kv.z); ku[3] = f2bf(kv.w);
            *(ushortx4*)&fK[row * LK + c4] = ku;
            const float* vp = V + (size_t)(k0 + row) * ROWSTRIDE + h * D_ + c4;
            float4 vv = *(const float4*)vp;
            fVT[(c4 + 0) * LK + row] = f2bf(vv.x);
            fVT[(c4 + 1) * LK + row] = f2bf(vv.y);
            fVT[(c4 + 2) * LK + row] = f2bf(vv.z);
            fVT[(c4 + 3) * LK + row] = f2bf(vv.w);
        }
        __syncthreads();
        f4 s[4];
        #pragma unroll
        for (int t = 0; t < 4; ++t) {
            f4 acc = {0,0,0,0};
            #pragma unroll
            for (int c = 0; c < 2; ++c) {
                bf16x8 kf = as_bf16x8(*(ushortx8*)&fK[(t * 16 + m16) * LK + c * 32 + g * 8]);
                acc = __builtin_amdgcn_mfma_f32_16x16x32_bf16(qf[c], kf, acc, 0, 0, 0);
            }
            s[t] = acc * SM_SCALE;
        }
        float mnew[4], rsum[4];
        #pragma unroll
        for (int r = 0; r < 4; ++r) {
            float pm = fmaxf(fmaxf(s[0][r], s[1][r]), fmaxf(s[2][r], s[3][r]));
            #pragma unroll
            for (int msk = 1; msk <= 8; msk <<= 1) pm = fmaxf(pm, __shfl_xor(pm, msk, 64));
            mnew[r] = fmaxf(mrow[r], pm);
            rsum[r] = 0.f;
        }
        #pragma unroll
        for (int t = 0; t < 4; ++t) {
            #pragma unroll
            for (int r = 0; r < 4; ++r) {
                float p = EXP2F((s[t][r] - mnew[r]) * LOG2E);
                rsum[r] += p;
                myP[(g * 4 + r) * LP + t * 16 + m16] = f2bf(p);
            }
        }
        #pragma unroll
        for (int r = 0; r < 4; ++r) {
            #pragma unroll
            for (int msk = 1; msk <= 8; msk <<= 1) rsum[r] += __shfl_xor(rsum[r], msk, 64);
            float alpha = EXP2F((mrow[r] - mnew[r]) * LOG2E);
            lrow[r] = lrow[r] * alpha + rsum[r];
            mrow[r] = mnew[r];
            o[0][r] *= alpha; o[1][r] *= alpha; o[2][r] *= alpha; o[3][r] *= alpha;
        }
        #pragma unroll
        for (int c = 0; c < 2; ++c) {
            bf16x8 pf = as_bf16x8(*(ushortx8*)&myP[m16 * LP + c * 32 + g * 8]);
            #pragma unroll
            for (int t = 0; t < 4; ++t) {
                bf16x8 vf = as_bf16x8(*(ushortx8*)&fVT[(t * 16 + m16) * LK + c * 32 + g * 8]);
                o[t] = __builtin_amdgcn_mfma_f32_16x16x32_bf16(pf, vf, o[t], 0, 0, 0);
            }
        }
    }
    float* op = O + (size_t)q0 * ROWSTRIDE + h * D_;
    #pragma unroll
    for (int r = 0; r < 4; ++r) {
        float inv = 1.f / lrow[r];
        int row = g * 4 + r;
        #pragma unroll
        for (int t = 0; t < 4; ++t)
            op[(size_t)row * ROWSTRIDE + t * 16 + m16] = o[t][r] * inv;
    }
}

extern "C" void kernel_launch(void* const* d_in, const int* in_sizes, int n_in,
                              void* d_out, int out_size, void* d_ws, size_t ws_size,
                              hipStream_t stream) {
    const float* Q = (const float*)d_in[0];
    const float* K = (const float*)d_in[1];
    const float* V = (const float*)d_in[2];
    float* O = (float*)d_out;
    const size_t packed = (size_t)H_ * NT * TILE_USH;            // 4 Mi ushorts
    const size_t packed_bytes = 2 * packed * sizeof(ushort_t);   // 16 MiB
    if (ws_size >= packed_bytes) {
        ushort_t* Kp = (ushort_t*)d_ws;
        ushort_t* Vp = Kp + packed;
        pack_kv<<<dim3(H_ * NT), dim3(256), 0, stream>>>(K, V, Kp, Vp);
        usp_attn_fa8<<<dim3(H_ * (S_ / QB)), dim3(320), 0, stream>>>(Q, Kp, Vp, O);
    } else {
        usp_attn_fa<<<dim3(H_ * (S_ / 64)), dim3(256), 0, stream>>>(Q, K, V, O);
    }
}

// Round 10
// 175.062 us; speedup vs baseline: 1.5175x; 1.5175x over previous
//
#include <hip/hip_runtime.h>
#include <stdint.h>

#define H_ 16
#define S_ 4096
#define D_ 64
#define ROWSTRIDE (H_ * D_)   // 1024 floats between consecutive s rows
#define BK 64                 // keys per packed tile
#define NT (S_ / BK)          // 64 key tiles per head
#define NTH (NT / 2)          // 32 tiles per split-K half
#define TILE_USH (BK * D_)    // 4096 ushorts per packed 64x64 bf16 tile
#define NBUF 4                // ring depth (tiles) -> 64 KB; 2 blocks/CU => 132 KB < 160
#define BUF_USH (2 * TILE_USH)// K + V^T per ring slot = 16 KB
#define QB 256                // q-rows per block (4 fat waves x 64 q + producer)
#define LP 72
#define LK 72
#define QSCALE (0.125f * 1.44269504088896340736f)  // sm_scale * log2(e)
#define LOG2E 1.44269504088896340736f
#define SM_SCALE 0.125f

typedef unsigned short ushort_t;
typedef __attribute__((ext_vector_type(8))) __bf16 bf16x8;
typedef __attribute__((ext_vector_type(16))) float floatx16;
typedef __attribute__((ext_vector_type(8))) unsigned short ushortx8;
typedef __attribute__((ext_vector_type(4))) unsigned short ushortx4;

// exp2: single trans-pipe instruction (denorm flush fine for softmax).
#if __has_builtin(__builtin_amdgcn_exp2f)
#define EXP2F(x) __builtin_amdgcn_exp2f(x)
#else
__device__ inline float exp2_hw(float x) {
    float r; asm("v_exp_f32 %0, %1" : "=v"(r) : "v"(x)); return r;
}
#define EXP2F(x) exp2_hw(x)
#endif

__device__ inline unsigned short f2bf(float x) {   // RNE fp32->bf16 (scalar path)
    union { float f; unsigned int u; } c; c.f = x;
    unsigned int r = c.u + 0x7fffu + ((c.u >> 16) & 1u);
    return (unsigned short)(r >> 16);
}
// packed 2xfp32 -> 2xbf16 (RNE). No clang builtin on gfx950 -- single
// v_cvt_pk_bf16_f32 via inline asm. Proven R8: 100 -> 83.5 us.
__device__ inline uint32_t cvt_pk_bf16(float a, float b) {
#if __has_builtin(__builtin_amdgcn_cvt_pk_bf16_f32)
    auto r = __builtin_amdgcn_cvt_pk_bf16_f32(a, b);
    uint32_t u; __builtin_memcpy(&u, &r, 4); return u;
#else
    uint32_t r;
    asm("v_cvt_pk_bf16_f32 %0, %1, %2" : "=v"(r) : "v"(a), "v"(b));
    return r;
#endif
}
// C-layout -> B-operand half exchange (one v_permlane32_swap_b32 if available)
__device__ inline void permswap(uint32_t& a, uint32_t& b, int g2) {
#if __has_builtin(__builtin_amdgcn_permlane32_swap)
    auto r = __builtin_amdgcn_permlane32_swap(a, b, false, false);
    uint32_t tmp[2]; __builtin_memcpy(tmp, &r, 8);
    a = tmp[0]; b = tmp[1];
#else
    uint32_t ra = (uint32_t)__shfl_xor((int)a, 32, 64);
    uint32_t rb = (uint32_t)__shfl_xor((int)b, 32, 64);
    uint32_t na = g2 ? rb : a;
    uint32_t nb = g2 ? b : ra;
    a = na; b = nb;
#endif
}
__device__ inline bf16x8 as_bf16x8(ushortx8 v) {
    union { ushortx8 s; bf16x8 b; } c; c.s = v; return c.b;
}
__device__ inline bf16x8 bf16x8_from_u32(uint32_t a, uint32_t b, uint32_t c, uint32_t d) {
    union { uint32_t u[4]; bf16x8 b; } x; x.u[0]=a; x.u[1]=b; x.u[2]=c; x.u[3]=d; return x.b;
}
__device__ inline ushortx8 ushortx8_from_u32(uint32_t a, uint32_t b, uint32_t c, uint32_t d) {
    union { uint32_t u[4]; ushortx8 s; } x; x.u[0]=a; x.u[1]=b; x.u[2]=c; x.u[3]=d; return x.s;
}
__device__ inline void glds16(const void* g, void* l) {
    __builtin_amdgcn_global_load_lds(
        (const __attribute__((address_space(1))) void*)g,
        (__attribute__((address_space(3))) void*)l, 16, 0, 0);
}

// ---------------------------------------------------------------------------
// Pre-pass (proven zero-conflict): FRAGMENT-ORDERED packed tiles.
// K tile frag f=mk*4+c (1 KB): (lane,j) = K[tile*64+mk*32+(lane&31)][(2c+(lane>>5))*8+j]
// V tile frag f=md*4+kc (1 KB): (lane,j) = V[tile*64+(2kc+(lane>>5))*8+j][md*32+(lane&31)]
// ---------------------------------------------------------------------------
__global__ __launch_bounds__(256)
void pack_kv(const float* __restrict__ K, const float* __restrict__ V,
             ushort_t* __restrict__ Kp, ushort_t* __restrict__ Vp) {
    __shared__ ushort_t lT[D_ * 88];   // V^T scratch: lT[d*88 + key]
    const int tid = threadIdx.x;
    const int h = blockIdx.x & (H_ - 1);
    const int tile = blockIdx.x >> 4;
    ushort_t* kout = Kp + (size_t)(h * NT + tile) * TILE_USH;
    ushort_t* vout = Vp + (size_t)(h * NT + tile) * TILE_USH;

    #pragma unroll
    for (int p = 0; p < 2; ++p) {
        int idx = tid + p * 256;       // 0..511
        int f = idx >> 6;              // frag 0..7
        int lo = idx & 63;
        int mk = f >> 2, c = f & 3;
        int l31 = lo & 31, g2 = lo >> 5;
        const float* kp = K + (size_t)(tile * BK + mk * 32 + l31) * ROWSTRIDE + h * D_ + (2 * c + g2) * 8;
        float4 a = *(const float4*)kp;
        float4 b = *(const float4*)(kp + 4);
        *(ushortx8*)&kout[f * 512 + lo * 8] = ushortx8_from_u32(
            cvt_pk_bf16(a.x, a.y), cvt_pk_bf16(a.z, a.w),
            cvt_pk_bf16(b.x, b.y), cvt_pk_bf16(b.z, b.w));
    }

    #pragma unroll
    for (int p = 0; p < 4; ++p) {
        int idx = tid + p * 256;
        int row = idx >> 4;            // key 0..63
        int d4 = (idx & 15) * 4;
        const float* vp = V + (size_t)(tile * BK + row) * ROWSTRIDE + h * D_ + d4;
        float4 vv = *(const float4*)vp;
        lT[(d4 + 0) * 88 + row] = f2bf(vv.x);
        lT[(d4 + 1) * 88 + row] = f2bf(vv.y);
        lT[(d4 + 2) * 88 + row] = f2bf(vv.z);
        lT[(d4 + 3) * 88 + row] = f2bf(vv.w);
    }
    __syncthreads();
    #pragma unroll
    for (int p = 0; p < 2; ++p) {
        int idx = tid + p * 256;
        int f = idx >> 6;
        int lo = idx & 63;
        int md = f >> 2, kc = f & 3;
        int l31 = lo & 31, g2 = lo >> 5;
        ushortx8 u = *(ushortx8*)&lT[(md * 32 + l31) * 88 + (2 * kc + g2) * 8];
        *(ushortx8*)&vout[f * 512 + lo * 8] = u;
    }
}

// ---------------------------------------------------------------------------
// R17 split-K main kernel: the PROVEN R8 fat-wave schedule, applied to HALF
// the key tiles per block (kh in {0,1}). Grid 256 -> 512 = 2 blocks/CU
// (LDS 2x66 KB = 132 < 160; 10 waves, VGPR 116 -> 16-wave class, fits).
// Mechanism: R8 runs exactly 1 consumer wave/SIMD; MfmaUtil 34.5% means the
// matrix pipe idles ~65% in dep stalls (QK-chain drain -> exp2 stream ->
// PV-chain). A second INDEPENDENT wave/SIMD (different block, no shared
// flags, naturally de-phased) fills those gaps. R3's split-K null does not
// transfer: that 32q structure was LDS-throughput-saturated (196k cyc of
// ds_read_b128 vs 250k wall); the fat-wave structure reads 4x less (25%).
// Softmax is a pure sum -> exact combine: blocks emit unnormalized fp32
// partial O + row-sums; combine2 (verified in R3) finishes.
// Per-tile math is bit-identical to R8.
// ---------------------------------------------------------------------------
__global__ __launch_bounds__(320)
void usp_attn_fa8s(const float* __restrict__ Q, const ushort_t* __restrict__ Kp,
                   const ushort_t* __restrict__ Vp, float* __restrict__ Op,
                   float* __restrict__ Rs) {
    __shared__ __attribute__((aligned(16))) ushort_t smem[NBUF * BUF_USH];  // 64 KB ring
    __shared__ int flags[8];   // [0]=tiles staged; [4+w]=tiles consumed by wave w

    const int tid = threadIdx.x;
    const int lane = tid & 63;
    const int wv = tid >> 6;          // 0..3 consumers, 4 producer
    const int h = blockIdx.x & (H_ - 1);
    const int qi = (blockIdx.x >> 4) & 15;  // 0..15 (256 q-rows per block)
    const int kh = blockIdx.x >> 8;         // 0/1: key half
    const int l31 = lane & 31;
    const int g2 = lane >> 5;

    if (tid < 8) flags[tid] = 0;
    __syncthreads();                  // only block-wide barrier

    const ushort_t* kbase = Kp + ((size_t)h * NT + kh * NTH) * TILE_USH;
    const ushort_t* vbase = Vp + ((size_t)h * NT + kh * NTH) * TILE_USH;

    if (wv == 4) {
        // ---------------- producer (32 local tiles) ----------------
        for (int t = 0; t < NTH; ++t) {
            if (t >= NBUF) {
                for (;;) {
                    int m0 = __hip_atomic_load(&flags[4], __ATOMIC_ACQUIRE, __HIP_MEMORY_SCOPE_WORKGROUP);
                    int m1 = __hip_atomic_load(&flags[5], __ATOMIC_ACQUIRE, __HIP_MEMORY_SCOPE_WORKGROUP);
                    int m2 = __hip_atomic_load(&flags[6], __ATOMIC_ACQUIRE, __HIP_MEMORY_SCOPE_WORKGROUP);
                    int m3 = __hip_atomic_load(&flags[7], __ATOMIC_ACQUIRE, __HIP_MEMORY_SCOPE_WORKGROUP);
                    if (min(min(m0, m1), min(m2, m3)) >= t - (NBUF - 1)) break;
                    __builtin_amdgcn_s_sleep(1);
                }
            }
            const ushort_t* gK = kbase + (size_t)t * TILE_USH;
            const ushort_t* gV = vbase + (size_t)t * TILE_USH;
            ushort_t* bK = smem + (t & (NBUF - 1)) * BUF_USH;
            ushort_t* bV = bK + TILE_USH;
            #pragma unroll
            for (int i = 0; i < 8; ++i) {
                glds16(gK + i * 512 + lane * 8, bK + i * 512);
                glds16(gV + i * 512 + lane * 8, bV + i * 512);
            }
            __builtin_amdgcn_s_waitcnt(0x0f70);   // vmcnt(0) producer-local drain
            __hip_atomic_store(&flags[0], t + 1, __ATOMIC_RELEASE, __HIP_MEMORY_SCOPE_WORKGROUP);
        }
        return;
    }

    // ---------------- consumer: 64 q-rows (2 halves of 32) ------------------
    const int q0 = qi * QB + wv * 64;

    // Q^T B-frags per half: B[k: d=c*16+g2*8+j][n: q=l31], pre-scaled (log2)
    bf16x8 qf[2][4];
    #pragma unroll
    for (int qh = 0; qh < 2; ++qh) {
        const float* qp = Q + (size_t)(q0 + qh * 32 + l31) * ROWSTRIDE + h * D_ + g2 * 8;
        #pragma unroll
        for (int c = 0; c < 4; ++c) {
            const float4 v0 = *(const float4*)(qp + c * 16);
            const float4 v1 = *(const float4*)(qp + c * 16 + 4);
            qf[qh][c] = bf16x8_from_u32(
                cvt_pk_bf16(v0.x * QSCALE, v0.y * QSCALE),
                cvt_pk_bf16(v0.z * QSCALE, v0.w * QSCALE),
                cvt_pk_bf16(v1.x * QSCALE, v1.y * QSCALE),
                cvt_pk_bf16(v1.z * QSCALE, v1.w * QSCALE));
        }
    }

    floatx16 o[2][2] = {{{0,0,0,0,0,0,0,0,0,0,0,0,0,0,0,0},
                         {0,0,0,0,0,0,0,0,0,0,0,0,0,0,0,0}},
                        {{0,0,0,0,0,0,0,0,0,0,0,0,0,0,0,0},
                         {0,0,0,0,0,0,0,0,0,0,0,0,0,0,0,0}}};
    float rsa[2][2] = {{0.f, 0.f}, {0.f, 0.f}};   // per (qh, mk) partials

    for (int t = 0; t < NTH; ++t) {
        while (__hip_atomic_load(&flags[0], __ATOMIC_ACQUIRE, __HIP_MEMORY_SCOPE_WORKGROUP) < t + 1)
            __builtin_amdgcn_s_sleep(1);
        // lane-linear fragment base for this ring slot (zero-conflict reads)
        const ushortx8* fp = (const ushortx8*)(smem + (t & (NBUF - 1)) * BUF_USH) + lane;

        // --- K frags once into registers, reused for both q-halves
        bf16x8 ab[8];
        #pragma unroll
        for (int f = 0; f < 8; ++f) ab[f] = as_bf16x8(fp[f * 64]);

        // --- S^T = K Q^T : 4 independent 4-deep chains (qh x mk)
        floatx16 st[2][2];
        #pragma unroll
        for (int qh = 0; qh < 2; ++qh) {
            #pragma unroll
            for (int mk = 0; mk < 2; ++mk) {
                floatx16 acc = {0,0,0,0,0,0,0,0,0,0,0,0,0,0,0,0};
                #pragma unroll
                for (int c = 0; c < 4; ++c)
                    acc = __builtin_amdgcn_mfma_f32_32x32x16_bf16(ab[mk * 4 + c], qf[qh][c], acc, 0, 0, 0);
                st[qh][mk] = acc;
            }
        }

        // --- P = exp2(S'); pack pairs (1 cvt_pk each); per-mk denominators
        uint32_t qd[2][2][8];
        #pragma unroll
        for (int qh = 0; qh < 2; ++qh) {
            #pragma unroll
            for (int mk = 0; mk < 2; ++mk) {
                #pragma unroll
                for (int i = 0; i < 8; ++i) {
                    float p0 = EXP2F(st[qh][mk][2 * i]);
                    float p1 = EXP2F(st[qh][mk][2 * i + 1]);
                    rsa[qh][mk] += p0 + p1;
                    qd[qh][mk][i] = cvt_pk_bf16(p0, p1);
                }
            }
        }

        // --- V frags once, reused for both q-halves
        #pragma unroll
        for (int f = 0; f < 8; ++f) ab[f] = as_bf16x8(fp[512 + f * 64]);

        // --- O^T += V^T P^T : 4 key-chunks x 2 q-halves x 2 d-tiles
        #pragma unroll
        for (int kc = 0; kc < 4; ++kc) {
            int mk = kc >> 1, ci = kc & 1;
            #pragma unroll
            for (int qh = 0; qh < 2; ++qh) {
                uint32_t a0 = qd[qh][mk][ci * 4 + 0], a1 = qd[qh][mk][ci * 4 + 1];
                uint32_t b0 = qd[qh][mk][ci * 4 + 2], b1 = qd[qh][mk][ci * 4 + 3];
                permswap(a0, b0, g2);
                permswap(a1, b1, g2);
                bf16x8 pf = bf16x8_from_u32(a0, a1, b0, b1);
                #pragma unroll
                for (int md = 0; md < 2; ++md)
                    o[qh][md] = __builtin_amdgcn_mfma_f32_32x32x16_bf16(ab[md * 4 + kc], pf, o[qh][md], 0, 0, 0);
            }
        }

        __hip_atomic_store(&flags[4 + wv], t + 1, __ATOMIC_RELEASE, __HIP_MEMORY_SCOPE_WORKGROUP);
    }

    // --- epilogue: write UNNORMALIZED partials for this key half
    #pragma unroll
    for (int qh = 0; qh < 2; ++qh) {
        float r = rsa[qh][0] + rsa[qh][1];
        r += __shfl_xor(r, 32, 64);
        if (g2 == 0)
            Rs[(size_t)kh * S_ * H_ + (size_t)(q0 + qh * 32 + l31) * H_ + h] = r;
        float* op = Op + (size_t)kh * S_ * H_ * D_
                  + (size_t)(q0 + qh * 32 + l31) * ROWSTRIDE + h * D_;
        #pragma unroll
        for (int md = 0; md < 2; ++md) {
            #pragma unroll
            for (int rq = 0; rq < 4; ++rq) {
                int d0 = md * 32 + rq * 8 + 4 * g2;   // C row = (reg&3)+8*(reg>>2)+4*g2
                float4 w;
                w.x = o[qh][md][4 * rq + 0];
                w.y = o[qh][md][4 * rq + 1];
                w.z = o[qh][md][4 * rq + 2];
                w.w = o[qh][md][4 * rq + 3];
                *(float4*)&op[d0] = w;
            }
        }
    }
}

// ---------------------------------------------------------------------------
// Combine the two key-half partials: O = (o0 + o1) / (rs0 + rs1).
// Verified in R3. float4 per thread, fully coalesced, L2/L3-warm.
// ---------------------------------------------------------------------------
__global__ __launch_bounds__(256)
void combine2(const float* __restrict__ Op, const float* __restrict__ Rs,
              float* __restrict__ O) {
    const size_t i4 = (size_t)blockIdx.x * 256 + threadIdx.x;   // float4 idx
    const float4 x = ((const float4*)Op)[i4];
    const float4 y = ((const float4*)(Op + (size_t)S_ * H_ * D_))[i4];
    const int row = (int)(i4 >> 4);   // 16 float4 per (s,h) row
    const float inv = 1.f / (Rs[row] + Rs[row + S_ * H_]);
    float4 w;
    w.x = (x.x + y.x) * inv;
    w.y = (x.y + y.y) * inv;
    w.z = (x.z + y.z) * inv;
    w.w = (x.w + y.w) * inv;
    ((float4*)O)[i4] = w;
}

// ---------------------------------------------------------------------------
// Full-K fat-wave kernel (proven R8, 83.5 us): used when ws holds packed K/V
// but not the split-K partial buffers.
// ---------------------------------------------------------------------------
__global__ __launch_bounds__(320)
void usp_attn_fa8(const float* __restrict__ Q, const ushort_t* __restrict__ Kp,
                  const ushort_t* __restrict__ Vp, float* __restrict__ O) {
    __shared__ __attribute__((aligned(16))) ushort_t smem[NBUF * BUF_USH];  // 64 KB ring
    __shared__ int flags[8];

    const int tid = threadIdx.x;
    const int lane = tid & 63;
    const int wv = tid >> 6;
    const int h = blockIdx.x & (H_ - 1);
    const int qi = blockIdx.x >> 4;   // 0..15
    const int l31 = lane & 31;
    const int g2 = lane >> 5;

    if (tid < 8) flags[tid] = 0;
    __syncthreads();

    const ushort_t* kbase = Kp + (size_t)h * NT * TILE_USH;
    const ushort_t* vbase = Vp + (size_t)h * NT * TILE_USH;

    if (wv == 4) {
        for (int t = 0; t < NT; ++t) {
            if (t >= NBUF) {
                for (;;) {
                    int m0 = __hip_atomic_load(&flags[4], __ATOMIC_ACQUIRE, __HIP_MEMORY_SCOPE_WORKGROUP);
                    int m1 = __hip_atomic_load(&flags[5], __ATOMIC_ACQUIRE, __HIP_MEMORY_SCOPE_WORKGROUP);
                    int m2 = __hip_atomic_load(&flags[6], __ATOMIC_ACQUIRE, __HIP_MEMORY_SCOPE_WORKGROUP);
                    int m3 = __hip_atomic_load(&flags[7], __ATOMIC_ACQUIRE, __HIP_MEMORY_SCOPE_WORKGROUP);
                    if (min(min(m0, m1), min(m2, m3)) >= t - (NBUF - 1)) break;
                    __builtin_amdgcn_s_sleep(1);
                }
            }
            const ushort_t* gK = kbase + (size_t)t * TILE_USH;
            const ushort_t* gV = vbase + (size_t)t * TILE_USH;
            ushort_t* bK = smem + (t & (NBUF - 1)) * BUF_USH;
            ushort_t* bV = bK + TILE_USH;
            #pragma unroll
            for (int i = 0; i < 8; ++i) {
                glds16(gK + i * 512 + lane * 8, bK + i * 512);
                glds16(gV + i * 512 + lane * 8, bV + i * 512);
            }
            __builtin_amdgcn_s_waitcnt(0x0f70);
            __hip_atomic_store(&flags[0], t + 1, __ATOMIC_RELEASE, __HIP_MEMORY_SCOPE_WORKGROUP);
        }
        return;
    }

    const int q0 = qi * QB + wv * 64;
    bf16x8 qf[2][4];
    #pragma unroll
    for (int qh = 0; qh < 2; ++qh) {
        const float* qp = Q + (size_t)(q0 + qh * 32 + l31) * ROWSTRIDE + h * D_ + g2 * 8;
        #pragma unroll
        for (int c = 0; c < 4; ++c) {
            const float4 v0 = *(const float4*)(qp + c * 16);
            const float4 v1 = *(const float4*)(qp + c * 16 + 4);
            qf[qh][c] = bf16x8_from_u32(
                cvt_pk_bf16(v0.x * QSCALE, v0.y * QSCALE),
                cvt_pk_bf16(v0.z * QSCALE, v0.w * QSCALE),
                cvt_pk_bf16(v1.x * QSCALE, v1.y * QSCALE),
                cvt_pk_bf16(v1.z * QSCALE, v1.w * QSCALE));
        }
    }

    floatx16 o[2][2] = {{{0,0,0,0,0,0,0,0,0,0,0,0,0,0,0,0},
                         {0,0,0,0,0,0,0,0,0,0,0,0,0,0,0,0}},
                        {{0,0,0,0,0,0,0,0,0,0,0,0,0,0,0,0},
                         {0,0,0,0,0,0,0,0,0,0,0,0,0,0,0,0}}};
    float rsa[2][2] = {{0.f, 0.f}, {0.f, 0.f}};

    for (int t = 0; t < NT; ++t) {
        while (__hip_atomic_load(&flags[0], __ATOMIC_ACQUIRE, __HIP_MEMORY_SCOPE_WORKGROUP) < t + 1)
            __builtin_amdgcn_s_sleep(1);
        const ushortx8* fp = (const ushortx8*)(smem + (t & (NBUF - 1)) * BUF_USH) + lane;

        bf16x8 ab[8];
        #pragma unroll
        for (int f = 0; f < 8; ++f) ab[f] = as_bf16x8(fp[f * 64]);

        floatx16 st[2][2];
        #pragma unroll
        for (int qh = 0; qh < 2; ++qh) {
            #pragma unroll
            for (int mk = 0; mk < 2; ++mk) {
                floatx16 acc = {0,0,0,0,0,0,0,0,0,0,0,0,0,0,0,0};
                #pragma unroll
                for (int c = 0; c < 4; ++c)
                    acc = __builtin_amdgcn_mfma_f32_32x32x16_bf16(ab[mk * 4 + c], qf[qh][c], acc, 0, 0, 0);
                st[qh][mk] = acc;
            }
        }

        uint32_t qd[2][2][8];
        #pragma unroll
        for (int qh = 0; qh < 2; ++qh) {
            #pragma unroll
            for (int mk = 0; mk < 2; ++mk) {
                #pragma unroll
                for (int i = 0; i < 8; ++i) {
                    float p0 = EXP2F(st[qh][mk][2 * i]);
                    float p1 = EXP2F(st[qh][mk][2 * i + 1]);
                    rsa[qh][mk] += p0 + p1;
                    qd[qh][mk][i] = cvt_pk_bf16(p0, p1);
                }
            }
        }

        #pragma unroll
        for (int f = 0; f < 8; ++f) ab[f] = as_bf16x8(fp[512 + f * 64]);

        #pragma unroll
        for (int kc = 0; kc < 4; ++kc) {
            int mk = kc >> 1, ci = kc & 1;
            #pragma unroll
            for (int qh = 0; qh < 2; ++qh) {
                uint32_t a0 = qd[qh][mk][ci * 4 + 0], a1 = qd[qh][mk][ci * 4 + 1];
                uint32_t b0 = qd[qh][mk][ci * 4 + 2], b1 = qd[qh][mk][ci * 4 + 3];
                permswap(a0, b0, g2);
                permswap(a1, b1, g2);
                bf16x8 pf = bf16x8_from_u32(a0, a1, b0, b1);
                #pragma unroll
                for (int md = 0; md < 2; ++md)
                    o[qh][md] = __builtin_amdgcn_mfma_f32_32x32x16_bf16(ab[md * 4 + kc], pf, o[qh][md], 0, 0, 0);
            }
        }

        __hip_atomic_store(&flags[4 + wv], t + 1, __ATOMIC_RELEASE, __HIP_MEMORY_SCOPE_WORKGROUP);
    }

    #pragma unroll
    for (int qh = 0; qh < 2; ++qh) {
        float r = rsa[qh][0] + rsa[qh][1];
        r += __shfl_xor(r, 32, 64);
        float inv = 1.f / r;
        float* op = O + (size_t)(q0 + qh * 32 + l31) * ROWSTRIDE + h * D_;
        #pragma unroll
        for (int md = 0; md < 2; ++md) {
            #pragma unroll
            for (int rq = 0; rq < 4; ++rq) {
                int d0 = md * 32 + rq * 8 + 4 * g2;
                float4 w;
                w.x = o[qh][md][4 * rq + 0] * inv;
                w.y = o[qh][md][4 * rq + 1] * inv;
                w.z = o[qh][md][4 * rq + 2] * inv;
                w.w = o[qh][md][4 * rq + 3] * inv;
                *(float4*)&op[d0] = w;
            }
        }
    }
}

// ---------------------------------------------------------------------------
// Fallback (proven R1 kernel) if ws can't hold packed K/V.
// ---------------------------------------------------------------------------
__global__ __launch_bounds__(256, 2)
void usp_attn_fa(const float* __restrict__ Q, const float* __restrict__ K,
                 const float* __restrict__ V, float* __restrict__ O) {
    __shared__ unsigned short fK[BK * LK];
    __shared__ unsigned short fVT[D_ * LK];
    __shared__ unsigned short fP[4 * 16 * LP];
    const int tid = threadIdx.x;
    const int lane = tid & 63;
    const int wv = tid >> 6;
    const int h = blockIdx.x & (H_ - 1);
    const int qt = blockIdx.x >> 4;
    const int q0 = qt * 64 + wv * 16;
    const int m16 = lane & 15;
    const int g = lane >> 4;
    typedef __attribute__((ext_vector_type(4))) float f4;
    bf16x8 qf[2];
    {
        const float* qp = Q + (size_t)(q0 + m16) * ROWSTRIDE + h * D_ + g * 8;
        for (int c = 0; c < 2; ++c) {
            ushortx8 u;
            #pragma unroll
            for (int j = 0; j < 8; ++j) u[j] = f2bf(qp[c * 32 + j]);
            qf[c] = as_bf16x8(u);
        }
    }
    f4 o[4] = {{0,0,0,0},{0,0,0,0},{0,0,0,0},{0,0,0,0}};
    float mrow[4] = {-1e30f,-1e30f,-1e30f,-1e30f};
    float lrow[4] = {0.f,0.f,0.f,0.f};
    unsigned short* myP = &fP[wv * 16 * LP];
    for (int k0 = 0; k0 < S_; k0 += BK) {
        __syncthreads();
        #pragma unroll
        for (int p = 0; p < 4; ++p) {
            int idx = tid + p * 256;
            int row = idx >> 4;
            int c4 = (idx & 15) * 4;
            const float* kp = K + (size_t)(k0 + row) * ROWSTRIDE + h * D_ + c4;
            float4 kv = *(const float4*)kp;
            ushortx4 ku;
            ku[0] = f2bf(kv.x); ku[1] = f2bf(kv.y); ku[2] = f2bf(kv.z); ku[3] = f2bf(kv.w);
            *(ushortx4*)&fK[row * LK + c4] = ku;
            const float* vp = V + (size_t)(k0 + row) * ROWSTRIDE + h * D_ + c4;
            float4 vv = *(const float4*)vp;
            fVT[(c4 + 0) * LK + row] = f2bf(vv.x);
            fVT[(c4 + 1) * LK + row] = f2bf(vv.y);
            fVT[(c4 + 2) * LK + row] = f2bf(vv.z);
            fVT[(c4 + 3) * LK + row] = f2bf(vv.w);
        }
        __syncthreads();
        f4 s[4];
        #pragma unroll
        for (int t = 0; t < 4; ++t) {
            f4 acc = {0,0,0,0};
            #pragma unroll
            for (int c = 0; c < 2; ++c) {
                bf16x8 kf = as_bf16x8(*(ushortx8*)&fK[(t * 16 + m16) * LK + c * 32 + g * 8]);
                acc = __builtin_amdgcn_mfma_f32_16x16x32_bf16(qf[c], kf, acc, 0, 0, 0);
            }
            s[t] = acc * SM_SCALE;
        }
        float mnew[4], rsum[4];
        #pragma unroll
        for (int r = 0; r < 4; ++r) {
            float pm = fmaxf(fmaxf(s[0][r], s[1][r]), fmaxf(s[2][r], s[3][r]));
            #pragma unroll
            for (int msk = 1; msk <= 8; msk <<= 1) pm = fmaxf(pm, __shfl_xor(pm, msk, 64));
            mnew[r] = fmaxf(mrow[r], pm);
            rsum[r] = 0.f;
        }
        #pragma unroll
        for (int t = 0; t < 4; ++t) {
            #pragma unroll
            for (int r = 0; r < 4; ++r) {
                float p = EXP2F((s[t][r] - mnew[r]) * LOG2E);
                rsum[r] += p;
                myP[(g * 4 + r) * LP + t * 16 + m16] = f2bf(p);
            }
        }
        #pragma unroll
        for (int r = 0; r < 4; ++r) {
            #pragma unroll
            for (int msk = 1; msk <= 8; msk <<= 1) rsum[r] += __shfl_xor(rsum[r], msk, 64);
            float alpha = EXP2F((mrow[r] - mnew[r]) * LOG2E);
            lrow[r] = lrow[r] * alpha + rsum[r];
            mrow[r] = mnew[r];
            o[0][r] *= alpha; o[1][r] *= alpha; o[2][r] *= alpha; o[3][r] *= alpha;
        }
        #pragma unroll
        for (int c = 0; c < 2; ++c) {
            bf16x8 pf = as_bf16x8(*(ushortx8*)&myP[m16 * LP + c * 32 + g * 8]);
            #pragma unroll
            for (int t = 0; t < 4; ++t) {
                bf16x8 vf = as_bf16x8(*(ushortx8*)&fVT[(t * 16 + m16) * LK + c * 32 + g * 8]);
                o[t] = __builtin_amdgcn_mfma_f32_16x16x32_bf16(pf, vf, o[t], 0, 0, 0);
            }
        }
    }
    float* op = O + (size_t)q0 * ROWSTRIDE + h * D_;
    #pragma unroll
    for (int r = 0; r < 4; ++r) {
        float inv = 1.f / lrow[r];
        int row = g * 4 + r;
        #pragma unroll
        for (int t = 0; t < 4; ++t)
            op[(size_t)row * ROWSTRIDE + t * 16 + m16] = o[t][r] * inv;
    }
}

extern "C" void kernel_launch(void* const* d_in, const int* in_sizes, int n_in,
                              void* d_out, int out_size, void* d_ws, size_t ws_size,
                              hipStream_t stream) {
    const float* Q = (const float*)d_in[0];
    const float* K = (const float*)d_in[1];
    const float* V = (const float*)d_in[2];
    float* O = (float*)d_out;
    const size_t packed = (size_t)H_ * NT * TILE_USH;            // 4 Mi ushorts
    const size_t packed_bytes = 2 * packed * sizeof(ushort_t);   // 16 MiB
    const size_t oelem = (size_t)S_ * H_ * D_;                   // 4 Mi floats
    const size_t part_bytes = (2 * oelem + 2 * (size_t)S_ * H_) * sizeof(float); // ~32.5 MiB
    if (ws_size >= packed_bytes + part_bytes) {
        ushort_t* Kp = (ushort_t*)d_ws;
        ushort_t* Vp = Kp + packed;
        float* Op = (float*)(Vp + packed);        // 2 x S*H*D fp32 partials
        float* Rs = Op + 2 * oelem;               // 2 x S*H fp32 partial sums
        pack_kv<<<dim3(H_ * NT), dim3(256), 0, stream>>>(K, V, Kp, Vp);
        usp_attn_fa8s<<<dim3(H_ * 16 * 2), dim3(320), 0, stream>>>(Q, Kp, Vp, Op, Rs);
        combine2<<<dim3((unsigned)(oelem / 4 / 256)), dim3(256), 0, stream>>>(Op, Rs, O);
    } else if (ws_size >= packed_bytes) {
        ushort_t* Kp = (ushort_t*)d_ws;
        ushort_t* Vp = Kp + packed;
        pack_kv<<<dim3(H_ * NT), dim3(256), 0, stream>>>(K, V, Kp, Vp);
        usp_attn_fa8<<<dim3(H_ * (S_ / QB)), dim3(320), 0, stream>>>(Q, Kp, Vp, O);
    } else {
        usp_attn_fa<<<dim3(H_ * (S_ / 64)), dim3(256), 0, stream>>>(Q, K, V, O);
    }
}

// Round 11
// 173.534 us; speedup vs baseline: 1.5308x; 1.0088x over previous
//
#include <hip/hip_runtime.h>
#include <stdint.h>

#define H_ 16
#define S_ 4096
#define D_ 64
#define ROWSTRIDE (H_ * D_)   // 1024 floats between consecutive s rows
#define BK 64                 // keys per packed tile
#define NT (S_ / BK)          // 64 key tiles per head
#define NTH (NT / 2)          // 32 tiles per split-K half
#define TILE_USH (BK * D_)    // 4096 ushorts per packed 64x64 bf16 tile
#define NBUF 2                // ring depth: 32 KB LDS (33280 w/ flags).
                              // EMPIRICAL (R4/R5/R10 vs R0/R2/R3): 66048-B
                              // workgroups never co-reside (occupancy ~13%);
                              // 33280-B workgroups get 2 blocks/CU (~22-30%).
                              // NBUF=2 is the proven-co-resident footprint.
#define BUF_USH (2 * TILE_USH)// K + V^T per ring slot = 16 KB
#define QB 256                // q-rows per block (4 fat waves x 64 q + producer)
#define LP 72
#define LK 72
#define QSCALE (0.125f * 1.44269504088896340736f)  // sm_scale * log2(e)
#define LOG2E 1.44269504088896340736f
#define SM_SCALE 0.125f

typedef unsigned short ushort_t;
typedef __attribute__((ext_vector_type(8))) __bf16 bf16x8;
typedef __attribute__((ext_vector_type(16))) float floatx16;
typedef __attribute__((ext_vector_type(8))) unsigned short ushortx8;
typedef __attribute__((ext_vector_type(4))) unsigned short ushortx4;

// exp2: single trans-pipe instruction (denorm flush fine for softmax).
#if __has_builtin(__builtin_amdgcn_exp2f)
#define EXP2F(x) __builtin_amdgcn_exp2f(x)
#else
__device__ inline float exp2_hw(float x) {
    float r; asm("v_exp_f32 %0, %1" : "=v"(r) : "v"(x)); return r;
}
#define EXP2F(x) exp2_hw(x)
#endif

__device__ inline unsigned short f2bf(float x) {   // RNE fp32->bf16 (scalar path)
    union { float f; unsigned int u; } c; c.f = x;
    unsigned int r = c.u + 0x7fffu + ((c.u >> 16) & 1u);
    return (unsigned short)(r >> 16);
}
// packed 2xfp32 -> 2xbf16 (RNE). No clang builtin on gfx950 -- single
// v_cvt_pk_bf16_f32 via inline asm. Proven R8: 100 -> 83.5 us.
__device__ inline uint32_t cvt_pk_bf16(float a, float b) {
#if __has_builtin(__builtin_amdgcn_cvt_pk_bf16_f32)
    auto r = __builtin_amdgcn_cvt_pk_bf16_f32(a, b);
    uint32_t u; __builtin_memcpy(&u, &r, 4); return u;
#else
    uint32_t r;
    asm("v_cvt_pk_bf16_f32 %0, %1, %2" : "=v"(r) : "v"(a), "v"(b));
    return r;
#endif
}
// C-layout -> B-operand half exchange (one v_permlane32_swap_b32 if available)
__device__ inline void permswap(uint32_t& a, uint32_t& b, int g2) {
#if __has_builtin(__builtin_amdgcn_permlane32_swap)
    auto r = __builtin_amdgcn_permlane32_swap(a, b, false, false);
    uint32_t tmp[2]; __builtin_memcpy(tmp, &r, 8);
    a = tmp[0]; b = tmp[1];
#else
    uint32_t ra = (uint32_t)__shfl_xor((int)a, 32, 64);
    uint32_t rb = (uint32_t)__shfl_xor((int)b, 32, 64);
    uint32_t na = g2 ? rb : a;
    uint32_t nb = g2 ? b : ra;
    a = na; b = nb;
#endif
}
__device__ inline bf16x8 as_bf16x8(ushortx8 v) {
    union { ushortx8 s; bf16x8 b; } c; c.s = v; return c.b;
}
__device__ inline bf16x8 bf16x8_from_u32(uint32_t a, uint32_t b, uint32_t c, uint32_t d) {
    union { uint32_t u[4]; bf16x8 b; } x; x.u[0]=a; x.u[1]=b; x.u[2]=c; x.u[3]=d; return x.b;
}
__device__ inline ushortx8 ushortx8_from_u32(uint32_t a, uint32_t b, uint32_t c, uint32_t d) {
    union { uint32_t u[4]; ushortx8 s; } x; x.u[0]=a; x.u[1]=b; x.u[2]=c; x.u[3]=d; return x.s;
}
__device__ inline void glds16(const void* g, void* l) {
    __builtin_amdgcn_global_load_lds(
        (const __attribute__((address_space(1))) void*)g,
        (__attribute__((address_space(3))) void*)l, 16, 0, 0);
}

// ---------------------------------------------------------------------------
// Pre-pass (proven zero-conflict): FRAGMENT-ORDERED packed tiles.
// K tile frag f=mk*4+c (1 KB): (lane,j) = K[tile*64+mk*32+(lane&31)][(2c+(lane>>5))*8+j]
// V tile frag f=md*4+kc (1 KB): (lane,j) = V[tile*64+(2kc+(lane>>5))*8+j][md*32+(lane&31)]
// ---------------------------------------------------------------------------
__global__ __launch_bounds__(256)
void pack_kv(const float* __restrict__ K, const float* __restrict__ V,
             ushort_t* __restrict__ Kp, ushort_t* __restrict__ Vp) {
    __shared__ ushort_t lT[D_ * 88];   // V^T scratch: lT[d*88 + key]
    const int tid = threadIdx.x;
    const int h = blockIdx.x & (H_ - 1);
    const int tile = blockIdx.x >> 4;
    ushort_t* kout = Kp + (size_t)(h * NT + tile) * TILE_USH;
    ushort_t* vout = Vp + (size_t)(h * NT + tile) * TILE_USH;

    #pragma unroll
    for (int p = 0; p < 2; ++p) {
        int idx = tid + p * 256;       // 0..511
        int f = idx >> 6;              // frag 0..7
        int lo = idx & 63;
        int mk = f >> 2, c = f & 3;
        int l31 = lo & 31, g2 = lo >> 5;
        const float* kp = K + (size_t)(tile * BK + mk * 32 + l31) * ROWSTRIDE + h * D_ + (2 * c + g2) * 8;
        float4 a = *(const float4*)kp;
        float4 b = *(const float4*)(kp + 4);
        *(ushortx8*)&kout[f * 512 + lo * 8] = ushortx8_from_u32(
            cvt_pk_bf16(a.x, a.y), cvt_pk_bf16(a.z, a.w),
            cvt_pk_bf16(b.x, b.y), cvt_pk_bf16(b.z, b.w));
    }

    #pragma unroll
    for (int p = 0; p < 4; ++p) {
        int idx = tid + p * 256;
        int row = idx >> 4;            // key 0..63
        int d4 = (idx & 15) * 4;
        const float* vp = V + (size_t)(tile * BK + row) * ROWSTRIDE + h * D_ + d4;
        float4 vv = *(const float4*)vp;
        lT[(d4 + 0) * 88 + row] = f2bf(vv.x);
        lT[(d4 + 1) * 88 + row] = f2bf(vv.y);
        lT[(d4 + 2) * 88 + row] = f2bf(vv.z);
        lT[(d4 + 3) * 88 + row] = f2bf(vv.w);
    }
    __syncthreads();
    #pragma unroll
    for (int p = 0; p < 2; ++p) {
        int idx = tid + p * 256;
        int f = idx >> 6;
        int lo = idx & 63;
        int md = f >> 2, kc = f & 3;
        int l31 = lo & 31, g2 = lo >> 5;
        ushortx8 u = *(ushortx8*)&lT[(md * 32 + l31) * 88 + (2 * kc + g2) * 8];
        *(ushortx8*)&vout[f * 512 + lo * 8] = u;
    }
}

// ---------------------------------------------------------------------------
// R18 split-K main kernel: identical schedule/math to R17 (proven correct,
// 90.5 us), with NBUF=2 so the workgroup fits the EMPIRICAL co-residency
// footprint. R10's counters proved the 66048-B version never got 2 blocks/CU
// (occupancy 12.1 = R8's; VALUBusy/MfmaUtil scaled exactly as same-work-
// longer-wall), so the TLP hypothesis was never tested. With 33280 B (R0/R3-
// proven 2 blocks/CU), each SIMD hosts 2 INDEPENDENT consumer waves from
// different blocks (no shared flags, naturally de-phased) to fill the ~65%
// MFMA dep-stall gaps of the single-wave schedule.
// ---------------------------------------------------------------------------
__global__ __launch_bounds__(320)
void usp_attn_fa8s(const float* __restrict__ Q, const ushort_t* __restrict__ Kp,
                   const ushort_t* __restrict__ Vp, float* __restrict__ Op,
                   float* __restrict__ Rs) {
    __shared__ __attribute__((aligned(16))) ushort_t smem[NBUF * BUF_USH];  // 32 KB ring
    __shared__ int flags[8];   // [0]=tiles staged; [4+w]=tiles consumed by wave w

    const int tid = threadIdx.x;
    const int lane = tid & 63;
    const int wv = tid >> 6;          // 0..3 consumers, 4 producer
    const int h = blockIdx.x & (H_ - 1);
    const int qi = (blockIdx.x >> 4) & 15;  // 0..15 (256 q-rows per block)
    const int kh = blockIdx.x >> 8;         // 0/1: key half
    const int l31 = lane & 31;
    const int g2 = lane >> 5;

    if (tid < 8) flags[tid] = 0;
    __syncthreads();                  // only block-wide barrier

    const ushort_t* kbase = Kp + ((size_t)h * NT + kh * NTH) * TILE_USH;
    const ushort_t* vbase = Vp + ((size_t)h * NT + kh * NTH) * TILE_USH;

    if (wv == 4) {
        // ---------------- producer (32 local tiles) ----------------
        for (int t = 0; t < NTH; ++t) {
            if (t >= NBUF) {
                for (;;) {
                    int m0 = __hip_atomic_load(&flags[4], __ATOMIC_ACQUIRE, __HIP_MEMORY_SCOPE_WORKGROUP);
                    int m1 = __hip_atomic_load(&flags[5], __ATOMIC_ACQUIRE, __HIP_MEMORY_SCOPE_WORKGROUP);
                    int m2 = __hip_atomic_load(&flags[6], __ATOMIC_ACQUIRE, __HIP_MEMORY_SCOPE_WORKGROUP);
                    int m3 = __hip_atomic_load(&flags[7], __ATOMIC_ACQUIRE, __HIP_MEMORY_SCOPE_WORKGROUP);
                    if (min(min(m0, m1), min(m2, m3)) >= t - (NBUF - 1)) break;
                    __builtin_amdgcn_s_sleep(1);
                }
            }
            const ushort_t* gK = kbase + (size_t)t * TILE_USH;
            const ushort_t* gV = vbase + (size_t)t * TILE_USH;
            ushort_t* bK = smem + (t & (NBUF - 1)) * BUF_USH;
            ushort_t* bV = bK + TILE_USH;
            #pragma unroll
            for (int i = 0; i < 8; ++i) {
                glds16(gK + i * 512 + lane * 8, bK + i * 512);
                glds16(gV + i * 512 + lane * 8, bV + i * 512);
            }
            __builtin_amdgcn_s_waitcnt(0x0f70);   // vmcnt(0) producer-local drain
            __hip_atomic_store(&flags[0], t + 1, __ATOMIC_RELEASE, __HIP_MEMORY_SCOPE_WORKGROUP);
        }
        return;
    }

    // ---------------- consumer: 64 q-rows (2 halves of 32) ------------------
    const int q0 = qi * QB + wv * 64;

    // Q^T B-frags per half: B[k: d=c*16+g2*8+j][n: q=l31], pre-scaled (log2)
    bf16x8 qf[2][4];
    #pragma unroll
    for (int qh = 0; qh < 2; ++qh) {
        const float* qp = Q + (size_t)(q0 + qh * 32 + l31) * ROWSTRIDE + h * D_ + g2 * 8;
        #pragma unroll
        for (int c = 0; c < 4; ++c) {
            const float4 v0 = *(const float4*)(qp + c * 16);
            const float4 v1 = *(const float4*)(qp + c * 16 + 4);
            qf[qh][c] = bf16x8_from_u32(
                cvt_pk_bf16(v0.x * QSCALE, v0.y * QSCALE),
                cvt_pk_bf16(v0.z * QSCALE, v0.w * QSCALE),
                cvt_pk_bf16(v1.x * QSCALE, v1.y * QSCALE),
                cvt_pk_bf16(v1.z * QSCALE, v1.w * QSCALE));
        }
    }

    floatx16 o[2][2] = {{{0,0,0,0,0,0,0,0,0,0,0,0,0,0,0,0},
                         {0,0,0,0,0,0,0,0,0,0,0,0,0,0,0,0}},
                        {{0,0,0,0,0,0,0,0,0,0,0,0,0,0,0,0},
                         {0,0,0,0,0,0,0,0,0,0,0,0,0,0,0,0}}};
    float rsa[2][2] = {{0.f, 0.f}, {0.f, 0.f}};   // per (qh, mk) partials

    for (int t = 0; t < NTH; ++t) {
        while (__hip_atomic_load(&flags[0], __ATOMIC_ACQUIRE, __HIP_MEMORY_SCOPE_WORKGROUP) < t + 1)
            __builtin_amdgcn_s_sleep(1);
        // lane-linear fragment base for this ring slot (zero-conflict reads)
        const ushortx8* fp = (const ushortx8*)(smem + (t & (NBUF - 1)) * BUF_USH) + lane;

        // --- K frags once into registers, reused for both q-halves
        bf16x8 ab[8];
        #pragma unroll
        for (int f = 0; f < 8; ++f) ab[f] = as_bf16x8(fp[f * 64]);

        // --- S^T = K Q^T : 4 independent 4-deep chains (qh x mk)
        floatx16 st[2][2];
        #pragma unroll
        for (int qh = 0; qh < 2; ++qh) {
            #pragma unroll
            for (int mk = 0; mk < 2; ++mk) {
                floatx16 acc = {0,0,0,0,0,0,0,0,0,0,0,0,0,0,0,0};
                #pragma unroll
                for (int c = 0; c < 4; ++c)
                    acc = __builtin_amdgcn_mfma_f32_32x32x16_bf16(ab[mk * 4 + c], qf[qh][c], acc, 0, 0, 0);
                st[qh][mk] = acc;
            }
        }

        // --- P = exp2(S'); pack pairs (1 cvt_pk each); per-mk denominators
        uint32_t qd[2][2][8];
        #pragma unroll
        for (int qh = 0; qh < 2; ++qh) {
            #pragma unroll
            for (int mk = 0; mk < 2; ++mk) {
                #pragma unroll
                for (int i = 0; i < 8; ++i) {
                    float p0 = EXP2F(st[qh][mk][2 * i]);
                    float p1 = EXP2F(st[qh][mk][2 * i + 1]);
                    rsa[qh][mk] += p0 + p1;
                    qd[qh][mk][i] = cvt_pk_bf16(p0, p1);
                }
            }
        }

        // --- V frags once, reused for both q-halves
        #pragma unroll
        for (int f = 0; f < 8; ++f) ab[f] = as_bf16x8(fp[512 + f * 64]);

        // --- O^T += V^T P^T : 4 key-chunks x 2 q-halves x 2 d-tiles
        #pragma unroll
        for (int kc = 0; kc < 4; ++kc) {
            int mk = kc >> 1, ci = kc & 1;
            #pragma unroll
            for (int qh = 0; qh < 2; ++qh) {
                uint32_t a0 = qd[qh][mk][ci * 4 + 0], a1 = qd[qh][mk][ci * 4 + 1];
                uint32_t b0 = qd[qh][mk][ci * 4 + 2], b1 = qd[qh][mk][ci * 4 + 3];
                permswap(a0, b0, g2);
                permswap(a1, b1, g2);
                bf16x8 pf = bf16x8_from_u32(a0, a1, b0, b1);
                #pragma unroll
                for (int md = 0; md < 2; ++md)
                    o[qh][md] = __builtin_amdgcn_mfma_f32_32x32x16_bf16(ab[md * 4 + kc], pf, o[qh][md], 0, 0, 0);
            }
        }

        __hip_atomic_store(&flags[4 + wv], t + 1, __ATOMIC_RELEASE, __HIP_MEMORY_SCOPE_WORKGROUP);
    }

    // --- epilogue: write UNNORMALIZED partials for this key half
    #pragma unroll
    for (int qh = 0; qh < 2; ++qh) {
        float r = rsa[qh][0] + rsa[qh][1];
        r += __shfl_xor(r, 32, 64);
        if (g2 == 0)
            Rs[(size_t)kh * S_ * H_ + (size_t)(q0 + qh * 32 + l31) * H_ + h] = r;
        float* op = Op + (size_t)kh * S_ * H_ * D_
                  + (size_t)(q0 + qh * 32 + l31) * ROWSTRIDE + h * D_;
        #pragma unroll
        for (int md = 0; md < 2; ++md) {
            #pragma unroll
            for (int rq = 0; rq < 4; ++rq) {
                int d0 = md * 32 + rq * 8 + 4 * g2;   // C row = (reg&3)+8*(reg>>2)+4*g2
                float4 w;
                w.x = o[qh][md][4 * rq + 0];
                w.y = o[qh][md][4 * rq + 1];
                w.z = o[qh][md][4 * rq + 2];
                w.w = o[qh][md][4 * rq + 3];
                *(float4*)&op[d0] = w;
            }
        }
    }
}

// ---------------------------------------------------------------------------
// Combine the two key-half partials: O = (o0 + o1) / (rs0 + rs1).
// Verified in R3/R10. float4 per thread, fully coalesced, L2/L3-warm.
// ---------------------------------------------------------------------------
__global__ __launch_bounds__(256)
void combine2(const float* __restrict__ Op, const float* __restrict__ Rs,
              float* __restrict__ O) {
    const size_t i4 = (size_t)blockIdx.x * 256 + threadIdx.x;   // float4 idx
    const float4 x = ((const float4*)Op)[i4];
    const float4 y = ((const float4*)(Op + (size_t)S_ * H_ * D_))[i4];
    const int row = (int)(i4 >> 4);   // 16 float4 per (s,h) row
    const float inv = 1.f / (Rs[row] + Rs[row + S_ * H_]);
    float4 w;
    w.x = (x.x + y.x) * inv;
    w.y = (x.y + y.y) * inv;
    w.z = (x.z + y.z) * inv;
    w.w = (x.w + y.w) * inv;
    ((float4*)O)[i4] = w;
}

// ---------------------------------------------------------------------------
// Full-K fat-wave kernel (R8 schedule, NBUF=2 ring): used when ws holds
// packed K/V but not the split-K partial buffers.
// ---------------------------------------------------------------------------
__global__ __launch_bounds__(320)
void usp_attn_fa8(const float* __restrict__ Q, const ushort_t* __restrict__ Kp,
                  const ushort_t* __restrict__ Vp, float* __restrict__ O) {
    __shared__ __attribute__((aligned(16))) ushort_t smem[NBUF * BUF_USH];
    __shared__ int flags[8];

    const int tid = threadIdx.x;
    const int lane = tid & 63;
    const int wv = tid >> 6;
    const int h = blockIdx.x & (H_ - 1);
    const int qi = blockIdx.x >> 4;   // 0..15
    const int l31 = lane & 31;
    const int g2 = lane >> 5;

    if (tid < 8) flags[tid] = 0;
    __syncthreads();

    const ushort_t* kbase = Kp + (size_t)h * NT * TILE_USH;
    const ushort_t* vbase = Vp + (size_t)h * NT * TILE_USH;

    if (wv == 4) {
        for (int t = 0; t < NT; ++t) {
            if (t >= NBUF) {
                for (;;) {
                    int m0 = __hip_atomic_load(&flags[4], __ATOMIC_ACQUIRE, __HIP_MEMORY_SCOPE_WORKGROUP);
                    int m1 = __hip_atomic_load(&flags[5], __ATOMIC_ACQUIRE, __HIP_MEMORY_SCOPE_WORKGROUP);
                    int m2 = __hip_atomic_load(&flags[6], __ATOMIC_ACQUIRE, __HIP_MEMORY_SCOPE_WORKGROUP);
                    int m3 = __hip_atomic_load(&flags[7], __ATOMIC_ACQUIRE, __HIP_MEMORY_SCOPE_WORKGROUP);
                    if (min(min(m0, m1), min(m2, m3)) >= t - (NBUF - 1)) break;
                    __builtin_amdgcn_s_sleep(1);
                }
            }
            const ushort_t* gK = kbase + (size_t)t * TILE_USH;
            const ushort_t* gV = vbase + (size_t)t * TILE_USH;
            ushort_t* bK = smem + (t & (NBUF - 1)) * BUF_USH;
            ushort_t* bV = bK + TILE_USH;
            #pragma unroll
            for (int i = 0; i < 8; ++i) {
                glds16(gK + i * 512 + lane * 8, bK + i * 512);
                glds16(gV + i * 512 + lane * 8, bV + i * 512);
            }
            __builtin_amdgcn_s_waitcnt(0x0f70);
            __hip_atomic_store(&flags[0], t + 1, __ATOMIC_RELEASE, __HIP_MEMORY_SCOPE_WORKGROUP);
        }
        return;
    }

    const int q0 = qi * QB + wv * 64;
    bf16x8 qf[2][4];
    #pragma unroll
    for (int qh = 0; qh < 2; ++qh) {
        const float* qp = Q + (size_t)(q0 + qh * 32 + l31) * ROWSTRIDE + h * D_ + g2 * 8;
        #pragma unroll
        for (int c = 0; c < 4; ++c) {
            const float4 v0 = *(const float4*)(qp + c * 16);
            const float4 v1 = *(const float4*)(qp + c * 16 + 4);
            qf[qh][c] = bf16x8_from_u32(
                cvt_pk_bf16(v0.x * QSCALE, v0.y * QSCALE),
                cvt_pk_bf16(v0.z * QSCALE, v0.w * QSCALE),
                cvt_pk_bf16(v1.x * QSCALE, v1.y * QSCALE),
                cvt_pk_bf16(v1.z * QSCALE, v1.w * QSCALE));
        }
    }

    floatx16 o[2][2] = {{{0,0,0,0,0,0,0,0,0,0,0,0,0,0,0,0},
                         {0,0,0,0,0,0,0,0,0,0,0,0,0,0,0,0}},
                        {{0,0,0,0,0,0,0,0,0,0,0,0,0,0,0,0},
                         {0,0,0,0,0,0,0,0,0,0,0,0,0,0,0,0}}};
    float rsa[2][2] = {{0.f, 0.f}, {0.f, 0.f}};

    for (int t = 0; t < NT; ++t) {
        while (__hip_atomic_load(&flags[0], __ATOMIC_ACQUIRE, __HIP_MEMORY_SCOPE_WORKGROUP) < t + 1)
            __builtin_amdgcn_s_sleep(1);
        const ushortx8* fp = (const ushortx8*)(smem + (t & (NBUF - 1)) * BUF_USH) + lane;

        bf16x8 ab[8];
        #pragma unroll
        for (int f = 0; f < 8; ++f) ab[f] = as_bf16x8(fp[f * 64]);

        floatx16 st[2][2];
        #pragma unroll
        for (int qh = 0; qh < 2; ++qh) {
            #pragma unroll
            for (int mk = 0; mk < 2; ++mk) {
                floatx16 acc = {0,0,0,0,0,0,0,0,0,0,0,0,0,0,0,0};
                #pragma unroll
                for (int c = 0; c < 4; ++c)
                    acc = __builtin_amdgcn_mfma_f32_32x32x16_bf16(ab[mk * 4 + c], qf[qh][c], acc, 0, 0, 0);
                st[qh][mk] = acc;
            }
        }

        uint32_t qd[2][2][8];
        #pragma unroll
        for (int qh = 0; qh < 2; ++qh) {
            #pragma unroll
            for (int mk = 0; mk < 2; ++mk) {
                #pragma unroll
                for (int i = 0; i < 8; ++i) {
                    float p0 = EXP2F(st[qh][mk][2 * i]);
                    float p1 = EXP2F(st[qh][mk][2 * i + 1]);
                    rsa[qh][mk] += p0 + p1;
                    qd[qh][mk][i] = cvt_pk_bf16(p0, p1);
                }
            }
        }

        #pragma unroll
        for (int f = 0; f < 8; ++f) ab[f] = as_bf16x8(fp[512 + f * 64]);

        #pragma unroll
        for (int kc = 0; kc < 4; ++kc) {
            int mk = kc >> 1, ci = kc & 1;
            #pragma unroll
            for (int qh = 0; qh < 2; ++qh) {
                uint32_t a0 = qd[qh][mk][ci * 4 + 0], a1 = qd[qh][mk][ci * 4 + 1];
                uint32_t b0 = qd[qh][mk][ci * 4 + 2], b1 = qd[qh][mk][ci * 4 + 3];
                permswap(a0, b0, g2);
                permswap(a1, b1, g2);
                bf16x8 pf = bf16x8_from_u32(a0, a1, b0, b1);
                #pragma unroll
                for (int md = 0; md < 2; ++md)
                    o[qh][md] = __builtin_amdgcn_mfma_f32_32x32x16_bf16(ab[md * 4 + kc], pf, o[qh][md], 0, 0, 0);
            }
        }

        __hip_atomic_store(&flags[4 + wv], t + 1, __ATOMIC_RELEASE, __HIP_MEMORY_SCOPE_WORKGROUP);
    }

    #pragma unroll
    for (int qh = 0; qh < 2; ++qh) {
        float r = rsa[qh][0] + rsa[qh][1];
        r += __shfl_xor(r, 32, 64);
        float inv = 1.f / r;
        float* op = O + (size_t)(q0 + qh * 32 + l31) * ROWSTRIDE + h * D_;
        #pragma unroll
        for (int md = 0; md < 2; ++md) {
            #pragma unroll
            for (int rq = 0; rq < 4; ++rq) {
                int d0 = md * 32 + rq * 8 + 4 * g2;
                float4 w;
                w.x = o[qh][md][4 * rq + 0] * inv;
                w.y = o[qh][md][4 * rq + 1] * inv;
                w.z = o[qh][md][4 * rq + 2] * inv;
                w.w = o[qh][md][4 * rq + 3] * inv;
                *(float4*)&op[d0] = w;
            }
        }
    }
}

// ---------------------------------------------------------------------------
// Fallback (proven R1 kernel) if ws can't hold packed K/V.
// ---------------------------------------------------------------------------
__global__ __launch_bounds__(256, 2)
void usp_attn_fa(const float* __restrict__ Q, const float* __restrict__ K,
                 const float* __restrict__ V, float* __restrict__ O) {
    __shared__ unsigned short fK[BK * LK];
    __shared__ unsigned short fVT[D_ * LK];
    __shared__ unsigned short fP[4 * 16 * LP];
    const int tid = threadIdx.x;
    const int lane = tid & 63;
    const int wv = tid >> 6;
    const int h = blockIdx.x & (H_ - 1);
    const int qt = blockIdx.x >> 4;
    const int q0 = qt * 64 + wv * 16;
    const int m16 = lane & 15;
    const int g = lane >> 4;
    typedef __attribute__((ext_vector_type(4))) float f4;
    bf16x8 qf[2];
    {
        const float* qp = Q + (size_t)(q0 + m16) * ROWSTRIDE + h * D_ + g * 8;
        for (int c = 0; c < 2; ++c) {
            ushortx8 u;
            #pragma unroll
            for (int j = 0; j < 8; ++j) u[j] = f2bf(qp[c * 32 + j]);
            qf[c] = as_bf16x8(u);
        }
    }
    f4 o[4] = {{0,0,0,0},{0,0,0,0},{0,0,0,0},{0,0,0,0}};
    float mrow[4] = {-1e30f,-1e30f,-1e30f,-1e30f};
    float lrow[4] = {0.f,0.f,0.f,0.f};
    unsigned short* myP = &fP[wv * 16 * LP];
    for (int k0 = 0; k0 < S_; k0 += BK) {
        __syncthreads();
        #pragma unroll
        for (int p = 0; p < 4; ++p) {
            int idx = tid + p * 256;
            int row = idx >> 4;
            int c4 = (idx & 15) * 4;
            const float* kp = K + (size_t)(k0 + row) * ROWSTRIDE + h * D_ + c4;
            float4 kv = *(const float4*)kp;
            ushortx4 ku;
            ku[0] = f2bf(kv.x); ku[1] = f2bf(kv.y); ku[2] = f2bf(kv.z); ku[3] = f2bf(kv.w);
            *(ushortx4*)&fK[row * LK + c4] = ku;
            const float* vp = V + (size_t)(k0 + row) * ROWSTRIDE + h * D_ + c4;
            float4 vv = *(const float4*)vp;
            fVT[(c4 + 0) * LK + row] = f2bf(vv.x);
            fVT[(c4 + 1) * LK + row] = f2bf(vv.y);
            fVT[(c4 + 2) * LK + row] = f2bf(vv.z);
            fVT[(c4 + 3) * LK + row] = f2bf(vv.w);
        }
        __syncthreads();
        f4 s[4];
        #pragma unroll
        for (int t = 0; t < 4; ++t) {
            f4 acc = {0,0,0,0};
            #pragma unroll
            for (int c = 0; c < 2; ++c) {
                bf16x8 kf = as_bf16x8(*(ushortx8*)&fK[(t * 16 + m16) * LK + c * 32 + g * 8]);
                acc = __builtin_amdgcn_mfma_f32_16x16x32_bf16(qf[c], kf, acc, 0, 0, 0);
            }
            s[t] = acc * SM_SCALE;
        }
        float mnew[4], rsum[4];
        #pragma unroll
        for (int r = 0; r < 4; ++r) {
            float pm = fmaxf(fmaxf(s[0][r], s[1][r]), fmaxf(s[2][r], s[3][r]));
            #pragma unroll
            for (int msk = 1; msk <= 8; msk <<= 1) pm = fmaxf(pm, __shfl_xor(pm, msk, 64));
            mnew[r] = fmaxf(mrow[r], pm);
            rsum[r] = 0.f;
        }
        #pragma unroll
        for (int t = 0; t < 4; ++t) {
            #pragma unroll
            for (int r = 0; r < 4; ++r) {
                float p = EXP2F((s[t][r] - mnew[r]) * LOG2E);
                rsum[r] += p;
                myP[(g * 4 + r) * LP + t * 16 + m16] = f2bf(p);
            }
        }
        #pragma unroll
        for (int r = 0; r < 4; ++r) {
            #pragma unroll
            for (int msk = 1; msk <= 8; msk <<= 1) rsum[r] += __shfl_xor(rsum[r], msk, 64);
            float alpha = EXP2F((mrow[r] - mnew[r]) * LOG2E);
            lrow[r] = lrow[r] * alpha + rsum[r];
            mrow[r] = mnew[r];
            o[0][r] *= alpha; o[1][r] *= alpha; o[2][r] *= alpha; o[3][r] *= alpha;
        }
        #pragma unroll
        for (int c = 0; c < 2; ++c) {
            bf16x8 pf = as_bf16x8(*(ushortx8*)&myP[m16 * LP + c * 32 + g * 8]);
            #pragma unroll
            for (int t = 0; t < 4; ++t) {
                bf16x8 vf = as_bf16x8(*(ushortx8*)&fVT[(t * 16 + m16) * LK + c * 32 + g * 8]);
                o[t] = __builtin_amdgcn_mfma_f32_16x16x32_bf16(pf, vf, o[t], 0, 0, 0);
            }
        }
    }
    float* op = O + (size_t)q0 * ROWSTRIDE + h * D_;
    #pragma unroll
    for (int r = 0; r < 4; ++r) {
        float inv = 1.f / lrow[r];
        int row = g * 4 + r;
        #pragma unroll
        for (int t = 0; t < 4; ++t)
            op[(size_t)row * ROWSTRIDE + t * 16 + m16] = o[t][r] * inv;
    }
}

extern "C" void kernel_launch(void* const* d_in, const int* in_sizes, int n_in,
                              void* d_out, int out_size, void* d_ws, size_t ws_size,
                              hipStream_t stream) {
    const float* Q = (const float*)d_in[0];
    const float* K = (const float*)d_in[1];
    const float* V = (const float*)d_in[2];
    float* O = (float*)d_out;
    const size_t packed = (size_t)H_ * NT * TILE_USH;            // 4 Mi ushorts
    const size_t packed_bytes = 2 * packed * sizeof(ushort_t);   // 16 MiB
    const size_t oelem = (size_t)S_ * H_ * D_;                   // 4 Mi floats
    const size_t part_bytes = (2 * oelem + 2 * (size_t)S_ * H_) * sizeof(float); // ~32.5 MiB
    if (ws_size >= packed_bytes + part_bytes) {
        ushort_t* Kp = (ushort_t*)d_ws;
        ushort_t* Vp = Kp + packed;
        float* Op = (float*)(Vp + packed);        // 2 x S*H*D fp32 partials
        float* Rs = Op + 2 * oelem;               // 2 x S*H fp32 partial sums
        pack_kv<<<dim3(H_ * NT), dim3(256), 0, stream>>>(K, V, Kp, Vp);
        usp_attn_fa8s<<<dim3(H_ * 16 * 2), dim3(320), 0, stream>>>(Q, Kp, Vp, Op, Rs);
        combine2<<<dim3((unsigned)(oelem / 4 / 256)), dim3(256), 0, stream>>>(Op, Rs, O);
    } else if (ws_size >= packed_bytes) {
        ushort_t* Kp = (ushort_t*)d_ws;
        ushort_t* Vp = Kp + packed;
        pack_kv<<<dim3(H_ * NT), dim3(256), 0, stream>>>(K, V, Kp, Vp);
        usp_attn_fa8<<<dim3(H_ * (S_ / QB)), dim3(320), 0, stream>>>(Q, Kp, Vp, O);
    } else {
        usp_attn_fa<<<dim3(H_ * (S_ / 64)), dim3(256), 0, stream>>>(Q, K, V, O);
    }
}

// Round 12
// 160.216 us; speedup vs baseline: 1.6581x; 1.0831x over previous
//
#include <hip/hip_runtime.h>
#include <stdint.h>

#define H_ 16
#define S_ 4096
#define D_ 64
#define ROWSTRIDE (H_ * D_)   // 1024 floats between consecutive s rows
#define BK 64                 // keys per packed tile
#define NT (S_ / BK)          // 64 key tiles per head
#define TILE_USH (BK * D_)    // 4096 ushorts per packed 64x64 bf16 tile
#define NBUF 4                // ring depth (tiles) -> 64 KB. Reg class pins us to
                              // 1 block/CU (R10/R11: co-residency is VGPR-gated,
                              // not LDS-gated), so large LDS is free.
#define BUF_USH (2 * TILE_USH)// K + V^T per ring slot = 16 KB
#define QB 256                // q-rows per block (4 fat waves x 64 q + producer)
#define LP 72
#define LK 72
#define QSCALE (0.125f * 1.44269504088896340736f)  // sm_scale * log2(e)
#define LOG2E 1.44269504088896340736f
#define SM_SCALE 0.125f

typedef unsigned short ushort_t;
typedef __attribute__((ext_vector_type(8))) __bf16 bf16x8;
typedef __attribute__((ext_vector_type(16))) float floatx16;
typedef __attribute__((ext_vector_type(8))) unsigned short ushortx8;
typedef __attribute__((ext_vector_type(4))) unsigned short ushortx4;

// exp2: single trans-pipe instruction (denorm flush fine for softmax).
#if __has_builtin(__builtin_amdgcn_exp2f)
#define EXP2F(x) __builtin_amdgcn_exp2f(x)
#else
__device__ inline float exp2_hw(float x) {
    float r; asm("v_exp_f32 %0, %1" : "=v"(r) : "v"(x)); return r;
}
#define EXP2F(x) exp2_hw(x)
#endif

__device__ inline unsigned short f2bf(float x) {   // RNE fp32->bf16 (scalar path)
    union { float f; unsigned int u; } c; c.f = x;
    unsigned int r = c.u + 0x7fffu + ((c.u >> 16) & 1u);
    return (unsigned short)(r >> 16);
}
// packed 2xfp32 -> 2xbf16 (RNE). No clang builtin on gfx950 -- single
// v_cvt_pk_bf16_f32 via inline asm. Proven R8: 100 -> 83.5 us.
__device__ inline uint32_t cvt_pk_bf16(float a, float b) {
#if __has_builtin(__builtin_amdgcn_cvt_pk_bf16_f32)
    auto r = __builtin_amdgcn_cvt_pk_bf16_f32(a, b);
    uint32_t u; __builtin_memcpy(&u, &r, 4); return u;
#else
    uint32_t r;
    asm("v_cvt_pk_bf16_f32 %0, %1, %2" : "=v"(r) : "v"(a), "v"(b));
    return r;
#endif
}
// C-layout -> B-operand half exchange (one v_permlane32_swap_b32 if available)
__device__ inline void permswap(uint32_t& a, uint32_t& b, int g2) {
#if __has_builtin(__builtin_amdgcn_permlane32_swap)
    auto r = __builtin_amdgcn_permlane32_swap(a, b, false, false);
    uint32_t tmp[2]; __builtin_memcpy(tmp, &r, 8);
    a = tmp[0]; b = tmp[1];
#else
    uint32_t ra = (uint32_t)__shfl_xor((int)a, 32, 64);
    uint32_t rb = (uint32_t)__shfl_xor((int)b, 32, 64);
    uint32_t na = g2 ? rb : a;
    uint32_t nb = g2 ? b : ra;
    a = na; b = nb;
#endif
}
__device__ inline bf16x8 as_bf16x8(ushortx8 v) {
    union { ushortx8 s; bf16x8 b; } c; c.s = v; return c.b;
}
__device__ inline bf16x8 bf16x8_from_u32(uint32_t a, uint32_t b, uint32_t c, uint32_t d) {
    union { uint32_t u[4]; bf16x8 b; } x; x.u[0]=a; x.u[1]=b; x.u[2]=c; x.u[3]=d; return x.b;
}
__device__ inline ushortx8 ushortx8_from_u32(uint32_t a, uint32_t b, uint32_t c, uint32_t d) {
    union { uint32_t u[4]; ushortx8 s; } x; x.u[0]=a; x.u[1]=b; x.u[2]=c; x.u[3]=d; return x.s;
}
__device__ inline void glds16(const void* g, void* l) {
    __builtin_amdgcn_global_load_lds(
        (const __attribute__((address_space(1))) void*)g,
        (__attribute__((address_space(3))) void*)l, 16, 0, 0);
}

// ---------------------------------------------------------------------------
// Pre-pass (proven zero-conflict): FRAGMENT-ORDERED packed tiles.
// K tile frag f=mk*4+c (1 KB): (lane,j) = K[tile*64+mk*32+(lane&31)][(2c+(lane>>5))*8+j]
// V tile frag f=md*4+kc (1 KB): (lane,j) = V[tile*64+(2kc+(lane>>5))*8+j][md*32+(lane&31)]
// ---------------------------------------------------------------------------
__global__ __launch_bounds__(256)
void pack_kv(const float* __restrict__ K, const float* __restrict__ V,
             ushort_t* __restrict__ Kp, ushort_t* __restrict__ Vp) {
    __shared__ ushort_t lT[D_ * 88];   // V^T scratch: lT[d*88 + key]
    const int tid = threadIdx.x;
    const int h = blockIdx.x & (H_ - 1);
    const int tile = blockIdx.x >> 4;
    ushort_t* kout = Kp + (size_t)(h * NT + tile) * TILE_USH;
    ushort_t* vout = Vp + (size_t)(h * NT + tile) * TILE_USH;

    #pragma unroll
    for (int p = 0; p < 2; ++p) {
        int idx = tid + p * 256;       // 0..511
        int f = idx >> 6;              // frag 0..7
        int lo = idx & 63;
        int mk = f >> 2, c = f & 3;
        int l31 = lo & 31, g2 = lo >> 5;
        const float* kp = K + (size_t)(tile * BK + mk * 32 + l31) * ROWSTRIDE + h * D_ + (2 * c + g2) * 8;
        float4 a = *(const float4*)kp;
        float4 b = *(const float4*)(kp + 4);
        *(ushortx8*)&kout[f * 512 + lo * 8] = ushortx8_from_u32(
            cvt_pk_bf16(a.x, a.y), cvt_pk_bf16(a.z, a.w),
            cvt_pk_bf16(b.x, b.y), cvt_pk_bf16(b.z, b.w));
    }

    #pragma unroll
    for (int p = 0; p < 4; ++p) {
        int idx = tid + p * 256;
        int row = idx >> 4;            // key 0..63
        int d4 = (idx & 15) * 4;
        const float* vp = V + (size_t)(tile * BK + row) * ROWSTRIDE + h * D_ + d4;
        float4 vv = *(const float4*)vp;
        lT[(d4 + 0) * 88 + row] = f2bf(vv.x);
        lT[(d4 + 1) * 88 + row] = f2bf(vv.y);
        lT[(d4 + 2) * 88 + row] = f2bf(vv.z);
        lT[(d4 + 3) * 88 + row] = f2bf(vv.w);
    }
    __syncthreads();
    #pragma unroll
    for (int p = 0; p < 2; ++p) {
        int idx = tid + p * 256;
        int f = idx >> 6;
        int lo = idx & 63;
        int md = f >> 2, kc = f & 3;
        int l31 = lo & 31, g2 = lo >> 5;
        ushortx8 u = *(ushortx8*)&lT[(md * 32 + l31) * 88 + (2 * kc + g2) * 8];
        *(ushortx8*)&vout[f * 512 + lo * 8] = u;
    }
}

// ---------------------------------------------------------------------------
// R19 main kernel: R8 fat-wave structure (proven 83.5 us) with two surgical
// intra-tile latency removals, exploiting the now-established fact that the
// fat-wave block is register-class-pinned to 1 block/CU (R10/R11) -- so
// register growth up to the next wave-class boundary is FREE (R9 died by
// crossing it with +128; this adds +32 and a reorder):
//  1. SEPARATE kk[8]/vv[8] buffers, all 16 ds_read_b128 issued at tile top.
//     R8's reused ab[] forced V reads to wait until after the last K-MFMA,
//     exposing their ~200-400 cyc latency between exp and PV. Now V loads
//     issue ~2000 cyc before first use: fully hidden.
//  2. Per-qh interleave: exp(qh0) -> PV(qh0) -> exp(qh1) -> PV(qh1).
//     PV(qh0)'s MFMAs execute while exp(qh1)'s trans-stream issues, and
//     exp(qh0) issues under QK(qh1)'s accumulator drain -- filling the two
//     biggest dead windows of the 3100-cyc tile.
// Sync structure, producer, math all bit-identical to R8.
// WRITE_SIZE is the spill canary: must stay ~16 MB (R9's spill showed 169).
// ---------------------------------------------------------------------------
__global__ __launch_bounds__(320)
void usp_attn_fa8(const float* __restrict__ Q, const ushort_t* __restrict__ Kp,
                  const ushort_t* __restrict__ Vp, float* __restrict__ O) {
    __shared__ __attribute__((aligned(16))) ushort_t smem[NBUF * BUF_USH];  // 64 KB ring
    __shared__ int flags[8];   // [0]=tiles staged; [4+w]=tiles consumed by wave w

    const int tid = threadIdx.x;
    const int lane = tid & 63;
    const int wv = tid >> 6;          // 0..3 consumers, 4 producer
    const int h = blockIdx.x & (H_ - 1);
    const int qi = blockIdx.x >> 4;   // 0..15 (256 q-rows per block)
    const int l31 = lane & 31;
    const int g2 = lane >> 5;

    if (tid < 8) flags[tid] = 0;
    __syncthreads();                  // only block-wide barrier

    const ushort_t* kbase = Kp + (size_t)h * NT * TILE_USH;
    const ushort_t* vbase = Vp + (size_t)h * NT * TILE_USH;

    if (wv == 4) {
        // ---------------- producer ----------------
        for (int t = 0; t < NT; ++t) {
            if (t >= NBUF) {
                for (;;) {
                    int m0 = __hip_atomic_load(&flags[4], __ATOMIC_ACQUIRE, __HIP_MEMORY_SCOPE_WORKGROUP);
                    int m1 = __hip_atomic_load(&flags[5], __ATOMIC_ACQUIRE, __HIP_MEMORY_SCOPE_WORKGROUP);
                    int m2 = __hip_atomic_load(&flags[6], __ATOMIC_ACQUIRE, __HIP_MEMORY_SCOPE_WORKGROUP);
                    int m3 = __hip_atomic_load(&flags[7], __ATOMIC_ACQUIRE, __HIP_MEMORY_SCOPE_WORKGROUP);
                    if (min(min(m0, m1), min(m2, m3)) >= t - (NBUF - 1)) break;
                    __builtin_amdgcn_s_sleep(1);
                }
            }
            const ushort_t* gK = kbase + (size_t)t * TILE_USH;
            const ushort_t* gV = vbase + (size_t)t * TILE_USH;
            ushort_t* bK = smem + (t & (NBUF - 1)) * BUF_USH;
            ushort_t* bV = bK + TILE_USH;
            #pragma unroll
            for (int i = 0; i < 8; ++i) {
                glds16(gK + i * 512 + lane * 8, bK + i * 512);
                glds16(gV + i * 512 + lane * 8, bV + i * 512);
            }
            __builtin_amdgcn_s_waitcnt(0x0f70);   // vmcnt(0) producer-local drain
            __hip_atomic_store(&flags[0], t + 1, __ATOMIC_RELEASE, __HIP_MEMORY_SCOPE_WORKGROUP);
        }
        return;
    }

    // ---------------- consumer: 64 q-rows (2 halves of 32) ------------------
    const int q0 = qi * QB + wv * 64;

    // Q^T B-frags per half: B[k: d=c*16+g2*8+j][n: q=l31], pre-scaled (log2)
    bf16x8 qf[2][4];
    #pragma unroll
    for (int qh = 0; qh < 2; ++qh) {
        const float* qp = Q + (size_t)(q0 + qh * 32 + l31) * ROWSTRIDE + h * D_ + g2 * 8;
        #pragma unroll
        for (int c = 0; c < 4; ++c) {
            const float4 v0 = *(const float4*)(qp + c * 16);
            const float4 v1 = *(const float4*)(qp + c * 16 + 4);
            qf[qh][c] = bf16x8_from_u32(
                cvt_pk_bf16(v0.x * QSCALE, v0.y * QSCALE),
                cvt_pk_bf16(v0.z * QSCALE, v0.w * QSCALE),
                cvt_pk_bf16(v1.x * QSCALE, v1.y * QSCALE),
                cvt_pk_bf16(v1.z * QSCALE, v1.w * QSCALE));
        }
    }

    floatx16 o[2][2] = {{{0,0,0,0,0,0,0,0,0,0,0,0,0,0,0,0},
                         {0,0,0,0,0,0,0,0,0,0,0,0,0,0,0,0}},
                        {{0,0,0,0,0,0,0,0,0,0,0,0,0,0,0,0},
                         {0,0,0,0,0,0,0,0,0,0,0,0,0,0,0,0}}};
    float rsa[2][2] = {{0.f, 0.f}, {0.f, 0.f}};   // per (qh, mk) partials

    for (int t = 0; t < NT; ++t) {
        while (__hip_atomic_load(&flags[0], __ATOMIC_ACQUIRE, __HIP_MEMORY_SCOPE_WORKGROUP) < t + 1)
            __builtin_amdgcn_s_sleep(1);
        // lane-linear fragment base for this ring slot (zero-conflict reads)
        const ushortx8* fp = (const ushortx8*)(smem + (t & (NBUF - 1)) * BUF_USH) + lane;

        // --- ALL 16 frag reads issued at tile top: V latency hides under
        //     QK + exp (separate buffers; no artificial reuse dependency).
        bf16x8 kk[8], vv[8];
        #pragma unroll
        for (int f = 0; f < 8; ++f) kk[f] = as_bf16x8(fp[f * 64]);
        #pragma unroll
        for (int f = 0; f < 8; ++f) vv[f] = as_bf16x8(fp[512 + f * 64]);

        // --- S^T = K Q^T : 4 independent 4-deep chains (qh x mk)
        floatx16 st[2][2];
        #pragma unroll
        for (int qh = 0; qh < 2; ++qh) {
            #pragma unroll
            for (int mk = 0; mk < 2; ++mk) {
                floatx16 acc = {0,0,0,0,0,0,0,0,0,0,0,0,0,0,0,0};
                #pragma unroll
                for (int c = 0; c < 4; ++c)
                    acc = __builtin_amdgcn_mfma_f32_32x32x16_bf16(kk[mk * 4 + c], qf[qh][c], acc, 0, 0, 0);
                st[qh][mk] = acc;
            }
        }

        // --- per-qh interleave: exp(qh) then PV(qh). PV(qh0) MFMAs overlap
        //     exp(qh1) trans issue; exp(qh0) issues under QK(qh1) drain.
        #pragma unroll
        for (int qh = 0; qh < 2; ++qh) {
            uint32_t qd[2][8];
            #pragma unroll
            for (int mk = 0; mk < 2; ++mk) {
                #pragma unroll
                for (int i = 0; i < 8; ++i) {
                    float p0 = EXP2F(st[qh][mk][2 * i]);
                    float p1 = EXP2F(st[qh][mk][2 * i + 1]);
                    rsa[qh][mk] += p0 + p1;
                    qd[mk][i] = cvt_pk_bf16(p0, p1);
                }
            }
            #pragma unroll
            for (int kc = 0; kc < 4; ++kc) {
                int mk = kc >> 1, ci = kc & 1;
                uint32_t a0 = qd[mk][ci * 4 + 0], a1 = qd[mk][ci * 4 + 1];
                uint32_t b0 = qd[mk][ci * 4 + 2], b1 = qd[mk][ci * 4 + 3];
                permswap(a0, b0, g2);
                permswap(a1, b1, g2);
                bf16x8 pf = bf16x8_from_u32(a0, a1, b0, b1);
                #pragma unroll
                for (int md = 0; md < 2; ++md)
                    o[qh][md] = __builtin_amdgcn_mfma_f32_32x32x16_bf16(vv[md * 4 + kc], pf, o[qh][md], 0, 0, 0);
            }
        }

        __hip_atomic_store(&flags[4 + wv], t + 1, __ATOMIC_RELEASE, __HIP_MEMORY_SCOPE_WORKGROUP);
    }

    // --- epilogue (per half, identical to proven R8 epilogue)
    #pragma unroll
    for (int qh = 0; qh < 2; ++qh) {
        float r = rsa[qh][0] + rsa[qh][1];
        r += __shfl_xor(r, 32, 64);
        float inv = 1.f / r;
        float* op = O + (size_t)(q0 + qh * 32 + l31) * ROWSTRIDE + h * D_;
        #pragma unroll
        for (int md = 0; md < 2; ++md) {
            #pragma unroll
            for (int rq = 0; rq < 4; ++rq) {
                int d0 = md * 32 + rq * 8 + 4 * g2;   // C row = (reg&3)+8*(reg>>2)+4*g2
                float4 w;
                w.x = o[qh][md][4 * rq + 0] * inv;
                w.y = o[qh][md][4 * rq + 1] * inv;
                w.z = o[qh][md][4 * rq + 2] * inv;
                w.w = o[qh][md][4 * rq + 3] * inv;
                *(float4*)&op[d0] = w;
            }
        }
    }
}

// ---------------------------------------------------------------------------
// Fallback (proven R1 kernel) if ws can't hold packed K/V.
// ---------------------------------------------------------------------------
__global__ __launch_bounds__(256, 2)
void usp_attn_fa(const float* __restrict__ Q, const float* __restrict__ K,
                 const float* __restrict__ V, float* __restrict__ O) {
    __shared__ unsigned short fK[BK * LK];
    __shared__ unsigned short fVT[D_ * LK];
    __shared__ unsigned short fP[4 * 16 * LP];
    const int tid = threadIdx.x;
    const int lane = tid & 63;
    const int wv = tid >> 6;
    const int h = blockIdx.x & (H_ - 1);
    const int qt = blockIdx.x >> 4;
    const int q0 = qt * 64 + wv * 16;
    const int m16 = lane & 15;
    const int g = lane >> 4;
    typedef __attribute__((ext_vector_type(4))) float f4;
    bf16x8 qf[2];
    {
        const float* qp = Q + (size_t)(q0 + m16) * ROWSTRIDE + h * D_ + g * 8;
        for (int c = 0; c < 2; ++c) {
            ushortx8 u;
            #pragma unroll
            for (int j = 0; j < 8; ++j) u[j] = f2bf(qp[c * 32 + j]);
            qf[c] = as_bf16x8(u);
        }
    }
    f4 o[4] = {{0,0,0,0},{0,0,0,0},{0,0,0,0},{0,0,0,0}};
    float mrow[4] = {-1e30f,-1e30f,-1e30f,-1e30f};
    float lrow[4] = {0.f,0.f,0.f,0.f};
    unsigned short* myP = &fP[wv * 16 * LP];
    for (int k0 = 0; k0 < S_; k0 += BK) {
        __syncthreads();
        #pragma unroll
        for (int p = 0; p < 4; ++p) {
            int idx = tid + p * 256;
            int row = idx >> 4;
            int c4 = (idx & 15) * 4;
            const float* kp = K + (size_t)(k0 + row) * ROWSTRIDE + h * D_ + c4;
            float4 kv = *(const float4*)kp;
            ushortx4 ku;
            ku[0] = f2bf(kv.x); ku[1] = f2bf(kv.y); ku[2] = f2bf(kv.z); ku[3] = f2bf(kv.w);
            *(ushortx4*)&fK[row * LK + c4] = ku;
            const float* vp = V + (size_t)(k0 + row) * ROWSTRIDE + h * D_ + c4;
            float4 vv = *(const float4*)vp;
            fVT[(c4 + 0) * LK + row] = f2bf(vv.x);
            fVT[(c4 + 1) * LK + row] = f2bf(vv.y);
            fVT[(c4 + 2) * LK + row] = f2bf(vv.z);
            fVT[(c4 + 3) * LK + row] = f2bf(vv.w);
        }
        __syncthreads();
        f4 s[4];
        #pragma unroll
        for (int t = 0; t < 4; ++t) {
            f4 acc = {0,0,0,0};
            #pragma unroll
            for (int c = 0; c < 2; ++c) {
                bf16x8 kf = as_bf16x8(*(ushortx8*)&fK[(t * 16 + m16) * LK + c * 32 + g * 8]);
                acc = __builtin_amdgcn_mfma_f32_16x16x32_bf16(qf[c], kf, acc, 0, 0, 0);
            }
            s[t] = acc * SM_SCALE;
        }
        float mnew[4], rsum[4];
        #pragma unroll
        for (int r = 0; r < 4; ++r) {
            float pm = fmaxf(fmaxf(s[0][r], s[1][r]), fmaxf(s[2][r], s[3][r]));
            #pragma unroll
            for (int msk = 1; msk <= 8; msk <<= 1) pm = fmaxf(pm, __shfl_xor(pm, msk, 64));
            mnew[r] = fmaxf(mrow[r], pm);
            rsum[r] = 0.f;
        }
        #pragma unroll
        for (int t = 0; t < 4; ++t) {
            #pragma unroll
            for (int r = 0; r < 4; ++r) {
                float p = EXP2F((s[t][r] - mnew[r]) * LOG2E);
                rsum[r] += p;
                myP[(g * 4 + r) * LP + t * 16 + m16] = f2bf(p);
            }
        }
        #pragma unroll
        for (int r = 0; r < 4; ++r) {
            #pragma unroll
            for (int msk = 1; msk <= 8; msk <<= 1) rsum[r] += __shfl_xor(rsum[r], msk, 64);
            float alpha = EXP2F((mrow[r] - mnew[r]) * LOG2E);
            lrow[r] = lrow[r] * alpha + rsum[r];
            mrow[r] = mnew[r];
            o[0][r] *= alpha; o[1][r] *= alpha; o[2][r] *= alpha; o[3][r] *= alpha;
        }
        #pragma unroll
        for (int c = 0; c < 2; ++c) {
            bf16x8 pf = as_bf16x8(*(ushortx8*)&myP[m16 * LP + c * 32 + g * 8]);
            #pragma unroll
            for (int t = 0; t < 4; ++t) {
                bf16x8 vf = as_bf16x8(*(ushortx8*)&fVT[(t * 16 + m16) * LK + c * 32 + g * 8]);
                o[t] = __builtin_amdgcn_mfma_f32_16x16x32_bf16(pf, vf, o[t], 0, 0, 0);
            }
        }
    }
    float* op = O + (size_t)q0 * ROWSTRIDE + h * D_;
    #pragma unroll
    for (int r = 0; r < 4; ++r) {
        float inv = 1.f / lrow[r];
        int row = g * 4 + r;
        #pragma unroll
        for (int t = 0; t < 4; ++t)
            op[(size_t)row * ROWSTRIDE + t * 16 + m16] = o[t][r] * inv;
    }
}

extern "C" void kernel_launch(void* const* d_in, const int* in_sizes, int n_in,
                              void* d_out, int out_size, void* d_ws, size_t ws_size,
                              hipStream_t stream) {
    const float* Q = (const float*)d_in[0];
    const float* K = (const float*)d_in[1];
    const float* V = (const float*)d_in[2];
    float* O = (float*)d_out;
    const size_t packed = (size_t)H_ * NT * TILE_USH;            // 4 Mi ushorts
    const size_t packed_bytes = 2 * packed * sizeof(ushort_t);   // 16 MiB
    if (ws_size >= packed_bytes) {
        ushort_t* Kp = (ushort_t*)d_ws;
        ushort_t* Vp = Kp + packed;
        pack_kv<<<dim3(H_ * NT), dim3(256), 0, stream>>>(K, V, Kp, Vp);
        usp_attn_fa8<<<dim3(H_ * (S_ / QB)), dim3(320), 0, stream>>>(Q, Kp, Vp, O);
    } else {
        usp_attn_fa<<<dim3(H_ * (S_ / 64)), dim3(256), 0, stream>>>(Q, K, V, O);
    }
}